// Round 11
// baseline (317.624 us; speedup 1.0000x reference)
//
#include <hip/hip_runtime.h>
#include <cstdint>
#include <cstddef>

namespace {

constexpr int N  = 50000;
constexpr int E  = 1600000;
constexpr int ET = E + N;          // edges + self loops
constexpr int F  = 256;
constexpr int H  = 6;
constexpr int C  = 16;
constexpr int HC = H * C;          // 96
constexpr int K  = 40;
constexpr int NBUCK = (N + 255) / 256;        // 196 coarse buckets (dst>>8)
constexpr int EPB2  = 8192;                   // edges per block in CSR passes
constexpr int HBLK  = (ET + EPB2 - 1) / EPB2; // 202

typedef __attribute__((ext_vector_type(8))) short short8;
typedef __attribute__((ext_vector_type(4))) float f32x4;
typedef __attribute__((ext_vector_type(2))) float f32x2;

__device__ inline uint32_t f2bf(float f) {  // RNE fp32 -> bf16
  uint32_t u = __float_as_uint(f);
  return (u + 0x7FFFu + ((u >> 16) & 1u)) >> 16;
}
__device__ inline float bflo(uint32_t u) { return __uint_as_float(u << 16); }
__device__ inline float bfhi(uint32_t u) { return __uint_as_float(u & 0xFFFF0000u); }

// ======== CSR via two-level LDS counting sort (NO global atomics) ========

__global__ void coarse_hist_kernel(const int* __restrict__ ei, int* __restrict__ hist) {
  __shared__ int h[256];
  const int t = threadIdx.x;
  h[t] = 0;
  __syncthreads();
  const int cbase = blockIdx.x * EPB2;
  const int cend = (cbase + EPB2 < ET) ? (cbase + EPB2) : ET;
  for (int e0 = cbase + t * 4; e0 < cend; e0 += 1024) {
    if (e0 + 3 < E && e0 + 3 < cend) {
      int4 dv = *reinterpret_cast<const int4*>(ei + E + e0);
      atomicAdd(&h[dv.x >> 8], 1);
      atomicAdd(&h[dv.y >> 8], 1);
      atomicAdd(&h[dv.z >> 8], 1);
      atomicAdd(&h[dv.w >> 8], 1);
    } else {
#pragma unroll
      for (int q = 0; q < 4; q++) {
        int e = e0 + q;
        if (e < cend) {
          int dd = (e < E) ? ei[E + e] : (e - E);
          atomicAdd(&h[dd >> 8], 1);
        }
      }
    }
  }
  __syncthreads();
  hist[blockIdx.x * 256 + t] = h[t];
}

__global__ void coarse_scan_kernel(const int* __restrict__ hist, int* __restrict__ base,
                                   int* __restrict__ bucket_base, int* __restrict__ rowp) {
  __shared__ int sc[256];
  const int d = threadIdx.x;
  int tot = 0;
#pragma unroll 4
  for (int b = 0; b < HBLK; b++) tot += hist[b * 256 + d];
  sc[d] = tot;
  __syncthreads();
  for (int off = 1; off < 256; off <<= 1) {
    int tv = (d >= off) ? sc[d - off] : 0;
    __syncthreads();
    sc[d] += tv;
    __syncthreads();
  }
  const int excl = sc[d] - tot;
  bucket_base[d] = excl;
  if (d == 255) {
    bucket_base[256] = sc[255];
    rowp[N] = sc[255];   // == ET
  }
  int run = excl;
#pragma unroll 4
  for (int b = 0; b < HBLK; b++) {
    int v = hist[b * 256 + d];
    base[b * 256 + d] = run;
    run += v;
  }
}

__global__ void coarse_scatter_kernel(const int* __restrict__ ei, const int* __restrict__ base,
                                      uint32_t* __restrict__ keys) {
  __shared__ int cnt[256];
  const int t = threadIdx.x;
  cnt[t] = base[blockIdx.x * 256 + t];
  __syncthreads();
  const int cbase = blockIdx.x * EPB2;
  const int cend = (cbase + EPB2 < ET) ? (cbase + EPB2) : ET;
  for (int e0 = cbase + t * 4; e0 < cend; e0 += 1024) {
    if (e0 + 3 < E && e0 + 3 < cend) {
      int4 dv = *reinterpret_cast<const int4*>(ei + E + e0);
      int4 sv = *reinterpret_cast<const int4*>(ei + e0);
      int p0 = atomicAdd(&cnt[dv.x >> 8], 1);
      keys[p0] = ((uint32_t)dv.x << 16) | (uint32_t)sv.x;
      int p1 = atomicAdd(&cnt[dv.y >> 8], 1);
      keys[p1] = ((uint32_t)dv.y << 16) | (uint32_t)sv.y;
      int p2 = atomicAdd(&cnt[dv.z >> 8], 1);
      keys[p2] = ((uint32_t)dv.z << 16) | (uint32_t)sv.z;
      int p3 = atomicAdd(&cnt[dv.w >> 8], 1);
      keys[p3] = ((uint32_t)dv.w << 16) | (uint32_t)sv.w;
    } else {
#pragma unroll
      for (int q = 0; q < 4; q++) {
        int e = e0 + q;
        if (e < cend) {
          int dd, ssrc;
          if (e < E) { dd = ei[E + e]; ssrc = ei[e]; }
          else       { dd = e - E; ssrc = e - E; }
          int p = atomicAdd(&cnt[dd >> 8], 1);
          keys[p] = ((uint32_t)dd << 16) | (uint32_t)ssrc;
        }
      }
    }
  }
}

__global__ void bucket_sort_kernel(const uint32_t* __restrict__ keys,
                                   const int* __restrict__ bucket_base,
                                   int* __restrict__ rowp, int* __restrict__ col) {
  __shared__ int hist[256];
  __shared__ int sc[256];
  __shared__ int ofs[256];
  const int b = blockIdx.x;
  const int t = threadIdx.x;
  hist[t] = 0;
  __syncthreads();
  const int k0 = bucket_base[b], k1 = bucket_base[b + 1];
  for (int i = k0 + t; i < k1; i += 256)
    atomicAdd(&hist[(keys[i] >> 16) & 255], 1);
  __syncthreads();
  const int v = hist[t];
  sc[t] = v;
  __syncthreads();
  for (int off = 1; off < 256; off <<= 1) {
    int tv = (t >= off) ? sc[t - off] : 0;
    __syncthreads();
    sc[t] += tv;
    __syncthreads();
  }
  ofs[t] = k0 + sc[t] - v;
  const int node = b * 256 + t;
  if (node < N) rowp[node] = ofs[t];
  hist[t] = 0;
  __syncthreads();
  for (int i = k0 + t; i < k1; i += 256) {
    uint32_t key = keys[i];
    int loc = (key >> 16) & 255;
    int p = ofs[loc] + atomicAdd(&hist[loc], 1);
    col[p] = (int)(key & 0xFFFFu);
  }
}

// ======== degree-sorted node permutation (equalize trip counts per wave) ========

__global__ void deg_hist_kernel(const int* __restrict__ rowp, int* __restrict__ dh) {
  __shared__ int h[256];
  const int t = threadIdx.x;
  h[t] = 0;
  __syncthreads();
  int i = blockIdx.x * 256 + t;
  if (i < N) {
    int deg = rowp[i + 1] - rowp[i];
    if (deg > 255) deg = 255;
    atomicAdd(&h[deg], 1);
  }
  __syncthreads();
  dh[blockIdx.x * 256 + t] = h[t];
}

__global__ void deg_scan_kernel(const int* __restrict__ dh, int* __restrict__ dbase) {
  __shared__ int sc[256];
  const int d = threadIdx.x;
  int tot = 0;
#pragma unroll 4
  for (int b = 0; b < NBUCK; b++) tot += dh[b * 256 + d];
  sc[d] = tot;
  __syncthreads();
  for (int off = 1; off < 256; off <<= 1) {
    int tv = (d >= off) ? sc[d - off] : 0;
    __syncthreads();
    sc[d] += tv;
    __syncthreads();
  }
  int run = sc[d] - tot;
#pragma unroll 4
  for (int b = 0; b < NBUCK; b++) {
    int v = dh[b * 256 + d];
    dbase[b * 256 + d] = run;
    run += v;
  }
}

__global__ void deg_scatter_kernel(const int* __restrict__ rowp, const int* __restrict__ dbase,
                                   int* __restrict__ perm) {
  __shared__ int cnt[256];
  const int t = threadIdx.x;
  cnt[t] = dbase[blockIdx.x * 256 + t];
  __syncthreads();
  int i = blockIdx.x * 256 + t;
  if (i < N) {
    int deg = rowp[i + 1] - rowp[i];
    if (deg > 255) deg = 255;
    int p = atomicAdd(&cnt[deg], 1);
    perm[p] = i;
  }
}

// ------- union prep: x -> bf16 pairs, and W1..W4 -> bf16 W^T -------

constexpr int TOB_N2 = N * (F / 2);                       // 6.4M u32
constexpr int T1 = 96 * 256, T2 = 96 * 96, T3 = 96 * 96, T4 = 48 * 96;
constexpr int CVT_T = T1 + T2 + T3 + T4;

__global__ void prep_kernel(const float* __restrict__ x, uint32_t* __restrict__ xB,
                            const float* __restrict__ W1, const float* __restrict__ W2,
                            const float* __restrict__ W3, const float* __restrict__ W4,
                            uint16_t* __restrict__ WT1, uint16_t* __restrict__ WT2,
                            uint16_t* __restrict__ WT3, uint16_t* __restrict__ WT4) {
  int t = blockIdx.x * 256 + threadIdx.x;
  if (t < TOB_N2) {
    float2 v = reinterpret_cast<const float2*>(x)[t];
    xB[t] = (f2bf(v.y) << 16) | f2bf(v.x);
    return;
  }
  t -= TOB_N2;
  if (t < T1) {
    int n = t / 256, k = t % 256;
    WT1[t] = (uint16_t)f2bf(W1[(size_t)k * 96 + n]);
  } else if (t < T1 + T2) {
    int u = t - T1; int n = u / 96, k = u % 96;
    WT2[u] = (uint16_t)f2bf(W2[(size_t)k * 96 + n]);
  } else if (t < T1 + T2 + T3) {
    int u = t - T1 - T2; int n = u / 96, k = u % 96;
    WT3[u] = (uint16_t)f2bf(W3[(size_t)k * 96 + n]);
  } else if (t < CVT_T) {
    int u = t - T1 - T2 - T3; int n = u / 96, k = u % 96;
    WT4[u] = (n < K) ? (uint16_t)f2bf(W4[(size_t)k * K + n]) : (uint16_t)0;
  }
}

// ---- fused MFMA GEMM + fp8-record pack (hidden layers, NCOLS=96) ----

template <int KD>
__launch_bounds__(256)
__global__ void gemm_pack_kernel(const uint32_t* __restrict__ A,
                                 const uint16_t* __restrict__ WT,
                                 const float* __restrict__ as_,
                                 const float* __restrict__ ad_,
                                 uint32_t* __restrict__ recs,
                                 float* __restrict__ aldP) {
  constexpr int KU = KD / 2;
  __shared__ float lds[64][97];
  const int wave = threadIdx.x >> 6;
  const int lane = threadIdx.x & 63;
  const int r = lane & 15, g = lane >> 4;
  const int m0 = (blockIdx.x * 4 + wave) * 16;
  int rowA = m0 + r;
  if (rowA > N - 1) rowA = N - 1;
  const uint32_t* arow = A + (size_t)rowA * KU + g * 4;
  const uint32_t* wt32 = reinterpret_cast<const uint32_t*>(WT);

  f32x4 acc[6];
#pragma unroll
  for (int nt = 0; nt < 6; nt++) acc[nt] = (f32x4){0.f, 0.f, 0.f, 0.f};

#pragma unroll
  for (int ks = 0; ks < KD / 32; ks++) {
    short8 av = *reinterpret_cast<const short8*>(arow + ks * 16);
#pragma unroll
    for (int nt = 0; nt < 6; nt++) {
      short8 bv = *reinterpret_cast<const short8*>(
          wt32 + (size_t)(nt * 16 + r) * KU + ks * 16 + g * 4);
      acc[nt] = __builtin_amdgcn_mfma_f32_16x16x32_bf16(av, bv, acc[nt], 0, 0, 0);
    }
  }

  const int lr0 = wave * 16 + g * 4;
#pragma unroll
  for (int nt = 0; nt < 6; nt++) {
#pragma unroll
    for (int t = 0; t < 4; t++) lds[lr0 + t][nt * 16 + r] = acc[nt][t];
  }
  __syncthreads();

  const int row = threadIdx.x >> 2;   // 0..63
  const int q = threadIdx.x & 3;      // 0..3
  const int grow = blockIdx.x * 64 + row;
  if (grow < N) {
    const float* lr = lds[row];
    uint32_t* rp = recs + (size_t)grow * 32;
#pragma unroll
    for (int w = 0; w < 6; w++) {
      const int c0 = q * 24 + w * 4;
      uint32_t wv = 0;
      wv = (uint32_t)__builtin_amdgcn_cvt_pk_fp8_f32(lr[c0], lr[c0 + 1], (int)wv, false);
      wv = (uint32_t)__builtin_amdgcn_cvt_pk_fp8_f32(lr[c0 + 2], lr[c0 + 3], (int)wv, true);
      rp[q * 6 + w] = wv;
    }
#pragma unroll
    for (int i = 0; i < 3; i++) {
      const int d = q * 3 + i;        // 12 dots: (head, s/d)
      const int hh = d >> 1;
      const float* av = (d & 1) ? ad_ : as_;
      float s = 0.f;
#pragma unroll
      for (int c = 0; c < 16; c++) s += lr[hh * 16 + c] * av[hh * 16 + c];
      if (d & 1) aldP[(size_t)grow * 8 + hh] = s;
      else       rp[24 + hh] = __float_as_uint(s);
    }
  }
}

// ---------------- plain MFMA GEMM (layer 4) ----------------

template <int KD, int NT, int NCOLS, int OST>
__launch_bounds__(256)
__global__ void mfma_gemm_kernel(const uint32_t* __restrict__ A,
                                 const uint16_t* __restrict__ WT,
                                 uint16_t* __restrict__ hOut, int M) {
  constexpr int KU = KD / 2;
  const int wave = threadIdx.x >> 6;
  const int lane = threadIdx.x & 63;
  const int m0 = (blockIdx.x * 4 + wave) * 16;
  if (m0 >= M) return;
  const int r = lane & 15, g = lane >> 4;
  int rowA = m0 + r;
  if (rowA > M - 1) rowA = M - 1;
  const uint32_t* arow = A + (size_t)rowA * KU + g * 4;
  const uint32_t* wt32 = reinterpret_cast<const uint32_t*>(WT);

  f32x4 acc[NT];
#pragma unroll
  for (int nt = 0; nt < NT; nt++) acc[nt] = (f32x4){0.f, 0.f, 0.f, 0.f};

#pragma unroll
  for (int ks = 0; ks < KD / 32; ks++) {
    short8 av = *reinterpret_cast<const short8*>(arow + ks * 16);
#pragma unroll
    for (int nt = 0; nt < NT; nt++) {
      short8 bv = *reinterpret_cast<const short8*>(
          wt32 + (size_t)(nt * 16 + r) * KU + ks * 16 + g * 4);
      acc[nt] = __builtin_amdgcn_mfma_f32_16x16x32_bf16(av, bv, acc[nt], 0, 0, 0);
    }
  }

  const int orow = m0 + g * 4;
#pragma unroll
  for (int nt = 0; nt < NT; nt++) {
    const int ocol = nt * 16 + r;
#pragma unroll
    for (int t = 0; t < 4; t++) {
      int rr = orow + t;
      if (rr < M && ocol < NCOLS)
        hOut[(size_t)rr * OST + ocol] = (uint16_t)f2bf(acc[nt][t]);
    }
  }
}

// Layer-4 record (16 u32 = 64B): words 0..9 = 40 fp8 ch, word 10 = als fp32.

__global__ void pack4_kernel(const uint32_t* __restrict__ h4B,
                             const float* __restrict__ as_, const float* __restrict__ ad_,
                             uint32_t* __restrict__ recs4, float* __restrict__ ald4) {
  int n = blockIdx.x * 256 + threadIdx.x;
  if (n >= N) return;
  const uint32_t* hp = h4B + (size_t)n * 32;
  float f[40];
  float ss = 0.f, dd = 0.f;
#pragma unroll
  for (int i = 0; i < 20; i++) {
    uint32_t u = hp[i];
    f[2 * i] = bflo(u);
    f[2 * i + 1] = bfhi(u);
  }
#pragma unroll
  for (int c = 0; c < 40; c++) {
    ss += f[c] * as_[c];
    dd += f[c] * ad_[c];
  }
  uint32_t* rp = recs4 + (size_t)n * 16;
#pragma unroll
  for (int q = 0; q < 10; q++) {
    uint32_t w = 0;
    w = (uint32_t)__builtin_amdgcn_cvt_pk_fp8_f32(f[4 * q + 0], f[4 * q + 1], (int)w, false);
    w = (uint32_t)__builtin_amdgcn_cvt_pk_fp8_f32(f[4 * q + 2], f[4 * q + 3], (int)w, true);
    rp[q] = w;
  }
  rp[10] = __float_as_uint(ss);
  ald4[n] = dd;
}

// ------- hidden-layer aggregate: 6 lanes/node (16 ch each), 10 nodes/wave -------
// Per iteration a wave serves 20 edge-halves (10 groups x 2 split halves); each
// lane's record load is one 16B dwordx4 covering a full head. li == head index.

__launch_bounds__(256)
__global__ void flash_agg6_kernel(const uint32_t* __restrict__ recs,
                                  const int* __restrict__ rowp,
                                  const int* __restrict__ col,
                                  const int* __restrict__ perm,
                                  const float* __restrict__ aldP,
                                  const float* __restrict__ bias,
                                  uint4* __restrict__ outB4) {
  const int lane = threadIdx.x & 63;
  const int wave = threadIdx.x >> 6;
  int g = lane / 6;
  if (g > 9) g = 9;
  int li = lane - g * 6;
  if (li > 5) li = 5;            // lanes 60-63 mirror group 9 lane 5 (benign dup)
  int idx = (blockIdx.x * 4 + wave) * 10 + g;
  if (idx > N - 1) idx = N - 1;
  const int n = perm[idx];
  const float aldv = aldP[(size_t)n * 8 + li];
  const int b0 = rowp[n];
  const int deg = rowp[n + 1] - b0;
  const int d1 = deg >> 1;       // half A: [0,d1)
  const int d2 = deg - d1;       // half B: [d1,deg)

  int km = d2;
#pragma unroll
  for (int off = 32; off > 0; off >>= 1) {
    int o = __shfl_xor(km, off);
    km = (o > km) ? o : km;
  }

  float accA[16], accB[16];
#pragma unroll
  for (int c = 0; c < 16; c++) { accA[c] = 0.f; accB[c] = 0.f; }
  float ssA = 0.f, ssB = 0.f;

#pragma unroll 2
  for (int k = 0; k < km; k++) {
    const bool vA = (k < d1);
    const bool vB = (k < d2);
    const int jA = b0 + (vA ? k : 0);
    const int jB = b0 + d1 + (vB ? k : 0);
    const int srcA = col[jA];
    const int srcB = col[jB];
    const uint32_t* recA = recs + (size_t)srcA * 32;
    const uint32_t* recB = recs + (size_t)srcB * 32;
    uint4 uA = *reinterpret_cast<const uint4*>(recA + 4 * li);
    uint4 uB = *reinterpret_cast<const uint4*>(recB + 4 * li);
    float lA = __uint_as_float(recA[24 + li]);
    float lB = __uint_as_float(recB[24 + li]);
    float eA = lA + aldv; eA = fmaxf(eA, 0.2f * eA);
    float eB = lB + aldv; eB = fmaxf(eB, 0.2f * eB);
    float pA = __expf(eA); pA = vA ? pA : 0.f;
    float pB = __expf(eB); pB = vB ? pB : 0.f;
    const uint32_t wa[4] = {uA.x, uA.y, uA.z, uA.w};
    const uint32_t wb[4] = {uB.x, uB.y, uB.z, uB.w};
#pragma unroll
    for (int w = 0; w < 4; w++) {
      f32x2 c0 = __builtin_amdgcn_cvt_pk_f32_fp8((int)wa[w], false);
      f32x2 c1 = __builtin_amdgcn_cvt_pk_f32_fp8((int)wa[w], true);
      accA[4 * w + 0] += pA * c0.x; accA[4 * w + 1] += pA * c0.y;
      accA[4 * w + 2] += pA * c1.x; accA[4 * w + 3] += pA * c1.y;
      f32x2 d0 = __builtin_amdgcn_cvt_pk_f32_fp8((int)wb[w], false);
      f32x2 dd1 = __builtin_amdgcn_cvt_pk_f32_fp8((int)wb[w], true);
      accB[4 * w + 0] += pB * d0.x; accB[4 * w + 1] += pB * d0.y;
      accB[4 * w + 2] += pB * dd1.x; accB[4 * w + 3] += pB * dd1.y;
    }
    ssA += pA; ssB += pB;
  }

  const float inv = 1.f / (ssA + ssB + 1e-16f);
  uint32_t wout[8];
#pragma unroll
  for (int j = 0; j < 8; j++) {
    float o0 = fmaxf((accA[2 * j] + accB[2 * j]) * inv + bias[16 * li + 2 * j], 0.f);
    float o1 = fmaxf((accA[2 * j + 1] + accB[2 * j + 1]) * inv + bias[16 * li + 2 * j + 1], 0.f);
    wout[j] = (f2bf(o1) << 16) | f2bf(o0);
  }
  outB4[(size_t)n * 12 + 2 * li]     = make_uint4(wout[0], wout[1], wout[2], wout[3]);
  outB4[(size_t)n * 12 + 2 * li + 1] = make_uint4(wout[4], wout[5], wout[6], wout[7]);
}

// ------- layer-4 aggregate + log_softmax (8 lanes/node, 8 nodes/wave) -------

__launch_bounds__(256)
__global__ void flash_agg_lsm_kernel(const uint32_t* __restrict__ recs,
                                     const int* __restrict__ rowp,
                                     const int* __restrict__ col,
                                     const int* __restrict__ perm,
                                     const float* __restrict__ aldP,
                                     const float* __restrict__ bias,
                                     float* __restrict__ outF32) {
  const int lane = threadIdx.x & 63;
  const int wave = threadIdx.x >> 6;
  const int g = lane >> 3;
  const int li = lane & 7;
  int idx = (blockIdx.x * 4 + wave) * 8 + g;
  if (idx > N - 1) idx = N - 1;
  const int n = perm[idx];
  const float aldv = aldP[n];
  const int b0 = rowp[n];
  const int deg = rowp[n + 1] - b0;
  const int d1 = deg >> 1;
  const int d2 = deg - d1;

  int km = d2;
#pragma unroll
  for (int off = 32; off > 0; off >>= 1) {
    int o = __shfl_xor(km, off);
    km = (o > km) ? o : km;
  }

  float a0 = 0.f, a1 = 0.f, a2 = 0.f, a3 = 0.f;
  float a4 = 0.f, a5 = 0.f, a6 = 0.f, a7 = 0.f;
  float b0f = 0.f, b1f = 0.f, b2f = 0.f, b3f = 0.f;
  float b4f = 0.f, b5f = 0.f, b6f = 0.f, b7f = 0.f;
  float ssA = 0.f, ssB = 0.f;

#pragma unroll 2
  for (int k = 0; k < km; k++) {
    const bool vA = (k < d1);
    const bool vB = (k < d2);
    const int jA = b0 + (vA ? k : 0);
    const int jB = b0 + d1 + (vB ? k : 0);
    const int srcA = col[jA];
    const int srcB = col[jB];
    const uint32_t* recA = recs + (size_t)srcA * 16;
    const uint32_t* recB = recs + (size_t)srcB * 16;
    uint2 uA = *reinterpret_cast<const uint2*>(recA + 2 * li);
    uint2 uB = *reinterpret_cast<const uint2*>(recB + 2 * li);
    float lA = __uint_as_float(recA[10]);
    float lB = __uint_as_float(recB[10]);
    float eA = lA + aldv; eA = fmaxf(eA, 0.2f * eA);
    float eB = lB + aldv; eB = fmaxf(eB, 0.2f * eB);
    float pA = __expf(eA); pA = vA ? pA : 0.f;
    float pB = __expf(eB); pB = vB ? pB : 0.f;
    f32x2 cA0 = __builtin_amdgcn_cvt_pk_f32_fp8((int)uA.x, false);
    f32x2 cA1 = __builtin_amdgcn_cvt_pk_f32_fp8((int)uA.x, true);
    f32x2 cA2 = __builtin_amdgcn_cvt_pk_f32_fp8((int)uA.y, false);
    f32x2 cA3 = __builtin_amdgcn_cvt_pk_f32_fp8((int)uA.y, true);
    f32x2 cB0 = __builtin_amdgcn_cvt_pk_f32_fp8((int)uB.x, false);
    f32x2 cB1 = __builtin_amdgcn_cvt_pk_f32_fp8((int)uB.x, true);
    f32x2 cB2 = __builtin_amdgcn_cvt_pk_f32_fp8((int)uB.y, false);
    f32x2 cB3 = __builtin_amdgcn_cvt_pk_f32_fp8((int)uB.y, true);
    a0 += pA * cA0.x; a1 += pA * cA0.y;
    a2 += pA * cA1.x; a3 += pA * cA1.y;
    a4 += pA * cA2.x; a5 += pA * cA2.y;
    a6 += pA * cA3.x; a7 += pA * cA3.y;
    ssA += pA;
    b0f += pB * cB0.x; b1f += pB * cB0.y;
    b2f += pB * cB1.x; b3f += pB * cB1.y;
    b4f += pB * cB2.x; b5f += pB * cB2.y;
    b6f += pB * cB3.x; b7f += pB * cB3.y;
    ssB += pB;
  }

  a0 += b0f; a1 += b1f; a2 += b2f; a3 += b3f;
  a4 += b4f; a5 += b5f; a6 += b6f; a7 += b7f;
  float inv = 1.f / (ssA + ssB + 1e-16f);

  bool vl = (li < 5);
  float v0 = vl ? a0 * inv + bias[8 * li + 0] : -1e30f;
  float v1 = vl ? a1 * inv + bias[8 * li + 1] : -1e30f;
  float v2 = vl ? a2 * inv + bias[8 * li + 2] : -1e30f;
  float v3 = vl ? a3 * inv + bias[8 * li + 3] : -1e30f;
  float v4 = vl ? a4 * inv + bias[8 * li + 4] : -1e30f;
  float v5 = vl ? a5 * inv + bias[8 * li + 5] : -1e30f;
  float v6 = vl ? a6 * inv + bias[8 * li + 6] : -1e30f;
  float v7 = vl ? a7 * inv + bias[8 * li + 7] : -1e30f;
  float mx = fmaxf(fmaxf(fmaxf(v0, v1), fmaxf(v2, v3)),
                   fmaxf(fmaxf(v4, v5), fmaxf(v6, v7)));
#pragma unroll
  for (int off = 1; off < 8; off <<= 1) mx = fmaxf(mx, __shfl_xor(mx, off));
  float es = 0.f;
  if (vl)
    es = __expf(v0 - mx) + __expf(v1 - mx) + __expf(v2 - mx) + __expf(v3 - mx) +
         __expf(v4 - mx) + __expf(v5 - mx) + __expf(v6 - mx) + __expf(v7 - mx);
#pragma unroll
  for (int off = 1; off < 8; off <<= 1) es += __shfl_xor(es, off);
  float lse = mx + __logf(es);
  if (vl) {
    float* op = outF32 + (size_t)n * K + li * 8;
    *reinterpret_cast<float4*>(op) = make_float4(v0 - lse, v1 - lse, v2 - lse, v3 - lse);
    *reinterpret_cast<float4*>(op + 4) = make_float4(v4 - lse, v5 - lse, v6 - lse, v7 - lse);
  }
}

inline int cdiv(int a, int b) { return (a + b - 1) / b; }

}  // namespace

extern "C" void kernel_launch(void* const* d_in, const int* in_sizes, int n_in,
                              void* d_out, int out_size, void* d_ws, size_t ws_size,
                              hipStream_t stream) {
  (void)in_sizes; (void)n_in; (void)out_size; (void)ws_size;
  const float* x   = (const float*)d_in[0];
  const int*   ei  = (const int*)d_in[1];
  const float* W1  = (const float*)d_in[2];
  const float* a1s = (const float*)d_in[3];
  const float* a1d = (const float*)d_in[4];
  const float* b1  = (const float*)d_in[5];
  const float* W2  = (const float*)d_in[6];
  const float* a2s = (const float*)d_in[7];
  const float* a2d = (const float*)d_in[8];
  const float* b2  = (const float*)d_in[9];
  const float* W3  = (const float*)d_in[10];
  const float* a3s = (const float*)d_in[11];
  const float* a3d = (const float*)d_in[12];
  const float* b3  = (const float*)d_in[13];
  const float* W4  = (const float*)d_in[14];
  const float* a4s = (const float*)d_in[15];
  const float* a4d = (const float*)d_in[16];
  const float* b4  = (const float*)d_in[17];
  float* out = (float*)d_out;

  char* ws = (char*)d_ws;
  size_t off = 0;
  auto alloc = [&](size_t bytes) {
    void* p = ws + off;
    off = (off + bytes + 255) & ~(size_t)255;
    return p;
  };
  int*      hist  = (int*)alloc((size_t)HBLK * 256 * 4);
  int*      basep = (int*)alloc((size_t)HBLK * 256 * 4);
  int*      bbase = (int*)alloc((size_t)257 * 4);
  int*      rowp  = (int*)alloc((size_t)(N + 1) * 4);
  uint32_t* keys  = (uint32_t*)alloc((size_t)ET * 4);
  int*      col   = (int*)alloc((size_t)ET * 4);
  int*      perm  = (int*)alloc((size_t)N * 4);
  uint32_t* xB    = (uint32_t*)alloc((size_t)N * (F / 2) * 4);
  uint16_t* WT1   = (uint16_t*)alloc((size_t)96 * 256 * 2);
  uint16_t* WT2   = (uint16_t*)alloc((size_t)96 * 96 * 2);
  uint16_t* WT3   = (uint16_t*)alloc((size_t)96 * 96 * 2);
  uint16_t* WT4   = (uint16_t*)alloc((size_t)48 * 96 * 2);
  uint32_t* actB  = (uint32_t*)alloc((size_t)N * (HC / 2) * 4);
  uint32_t* h4B   = (uint32_t*)alloc((size_t)N * 32 * 4);   // 64-ch padded bf16 rows
  uint32_t* recs  = (uint32_t*)alloc((size_t)N * 32 * 4);   // 128B records (fp8 h + als)
  uint32_t* recs4 = (uint32_t*)alloc((size_t)N * 16 * 4);   // 64B records (L4)
  float*    aldP  = (float*)alloc((size_t)N * 8 * 4);

  // ---- build CSR: LDS counting sort, zero global atomics ----
  coarse_hist_kernel<<<HBLK, 256, 0, stream>>>(ei, hist);
  coarse_scan_kernel<<<1, 256, 0, stream>>>(hist, basep, bbase, rowp);
  coarse_scatter_kernel<<<HBLK, 256, 0, stream>>>(ei, basep, keys);
  bucket_sort_kernel<<<NBUCK, 256, 0, stream>>>(keys, bbase, rowp, col);

  // ---- degree-sorted node permutation (reuses hist/basep scratch) ----
  deg_hist_kernel<<<NBUCK, 256, 0, stream>>>(rowp, hist);
  deg_scan_kernel<<<1, 256, 0, stream>>>(hist, basep);
  deg_scatter_kernel<<<NBUCK, 256, 0, stream>>>(rowp, basep, perm);

  // ---- dtype prep (x -> bf16, W -> W^T bf16) ----
  prep_kernel<<<cdiv(TOB_N2 + CVT_T, 256), 256, 0, stream>>>(
      x, xB, W1, W2, W3, W4, WT1, WT2, WT3, WT4);

  const int gN1  = cdiv(N, 256);
  const int gG   = cdiv(N, 64);     // GEMM: 4 waves x 16 rows per block
  const int gA96 = cdiv(N, 40);     // agg L1-3: 4 waves x 10 nodes
  const int gA40 = cdiv(N, 32);     // agg L4:   4 waves x 8 nodes

  // ---- layer 1 ----
  gemm_pack_kernel<F><<<gG, 256, 0, stream>>>(xB, WT1, a1s, a1d, recs, aldP);
  flash_agg6_kernel<<<gA96, 256, 0, stream>>>(recs, rowp, col, perm, aldP, b1, (uint4*)actB);

  // ---- layer 2 ----
  gemm_pack_kernel<HC><<<gG, 256, 0, stream>>>(actB, WT2, a2s, a2d, recs, aldP);
  flash_agg6_kernel<<<gA96, 256, 0, stream>>>(recs, rowp, col, perm, aldP, b2, (uint4*)actB);

  // ---- layer 3 ----
  gemm_pack_kernel<HC><<<gG, 256, 0, stream>>>(actB, WT3, a3s, a3d, recs, aldP);
  flash_agg6_kernel<<<gA96, 256, 0, stream>>>(recs, rowp, col, perm, aldP, b3, (uint4*)actB);

  // ---- layer 4 + log_softmax ----
  mfma_gemm_kernel<HC, 3, K, 64><<<gG, 256, 0, stream>>>(actB, WT4, (uint16_t*)h4B, N);
  pack4_kernel<<<gN1, 256, 0, stream>>>(h4B, a4s, a4d, recs4, aldP);
  flash_agg_lsm_kernel<<<gA40, 256, 0, stream>>>(recs4, rowp, col, perm, aldP, b4, out);
}

// Round 12
// 289.352 us; speedup vs baseline: 1.0977x; 1.0977x over previous
//
#include <hip/hip_runtime.h>
#include <cstdint>
#include <cstddef>

namespace {

constexpr int N  = 50000;
constexpr int E  = 1600000;
constexpr int ET = E + N;          // edges + self loops
constexpr int F  = 256;
constexpr int H  = 6;
constexpr int C  = 16;
constexpr int HC = H * C;          // 96
constexpr int K  = 40;
constexpr int NBUCK = (N + 255) / 256;        // 196 coarse buckets (dst>>8)
constexpr int EPB2  = 8192;                   // edges per block in CSR passes
constexpr int HBLK  = (ET + EPB2 - 1) / EPB2; // 202

typedef __attribute__((ext_vector_type(8))) short short8;
typedef __attribute__((ext_vector_type(4))) float f32x4;
typedef __attribute__((ext_vector_type(2))) float f32x2;

__device__ inline uint32_t f2bf(float f) {  // RNE fp32 -> bf16
  uint32_t u = __float_as_uint(f);
  return (u + 0x7FFFu + ((u >> 16) & 1u)) >> 16;
}
__device__ inline float bflo(uint32_t u) { return __uint_as_float(u << 16); }
__device__ inline float bfhi(uint32_t u) { return __uint_as_float(u & 0xFFFF0000u); }

// ======== CSR via two-level LDS counting sort (NO global atomics) ========

__global__ void coarse_hist_kernel(const int* __restrict__ ei, int* __restrict__ hist) {
  __shared__ int h[256];
  const int t = threadIdx.x;
  h[t] = 0;
  __syncthreads();
  const int cbase = blockIdx.x * EPB2;
  const int cend = (cbase + EPB2 < ET) ? (cbase + EPB2) : ET;
  for (int e0 = cbase + t * 4; e0 < cend; e0 += 1024) {
    if (e0 + 3 < E && e0 + 3 < cend) {
      int4 dv = *reinterpret_cast<const int4*>(ei + E + e0);
      atomicAdd(&h[dv.x >> 8], 1);
      atomicAdd(&h[dv.y >> 8], 1);
      atomicAdd(&h[dv.z >> 8], 1);
      atomicAdd(&h[dv.w >> 8], 1);
    } else {
#pragma unroll
      for (int q = 0; q < 4; q++) {
        int e = e0 + q;
        if (e < cend) {
          int dd = (e < E) ? ei[E + e] : (e - E);
          atomicAdd(&h[dd >> 8], 1);
        }
      }
    }
  }
  __syncthreads();
  hist[blockIdx.x * 256 + t] = h[t];
}

__global__ void coarse_scan_kernel(const int* __restrict__ hist, int* __restrict__ base,
                                   int* __restrict__ bucket_base, int* __restrict__ rowp) {
  __shared__ int sc[256];
  const int d = threadIdx.x;
  int tot = 0;
#pragma unroll 4
  for (int b = 0; b < HBLK; b++) tot += hist[b * 256 + d];
  sc[d] = tot;
  __syncthreads();
  for (int off = 1; off < 256; off <<= 1) {
    int tv = (d >= off) ? sc[d - off] : 0;
    __syncthreads();
    sc[d] += tv;
    __syncthreads();
  }
  const int excl = sc[d] - tot;
  bucket_base[d] = excl;
  if (d == 255) {
    bucket_base[256] = sc[255];
    rowp[N] = sc[255];   // == ET
  }
  int run = excl;
#pragma unroll 4
  for (int b = 0; b < HBLK; b++) {
    int v = hist[b * 256 + d];
    base[b * 256 + d] = run;
    run += v;
  }
}

__global__ void coarse_scatter_kernel(const int* __restrict__ ei, const int* __restrict__ base,
                                      uint32_t* __restrict__ keys) {
  __shared__ int cnt[256];
  const int t = threadIdx.x;
  cnt[t] = base[blockIdx.x * 256 + t];
  __syncthreads();
  const int cbase = blockIdx.x * EPB2;
  const int cend = (cbase + EPB2 < ET) ? (cbase + EPB2) : ET;
  for (int e0 = cbase + t * 4; e0 < cend; e0 += 1024) {
    if (e0 + 3 < E && e0 + 3 < cend) {
      int4 dv = *reinterpret_cast<const int4*>(ei + E + e0);
      int4 sv = *reinterpret_cast<const int4*>(ei + e0);
      int p0 = atomicAdd(&cnt[dv.x >> 8], 1);
      keys[p0] = ((uint32_t)dv.x << 16) | (uint32_t)sv.x;
      int p1 = atomicAdd(&cnt[dv.y >> 8], 1);
      keys[p1] = ((uint32_t)dv.y << 16) | (uint32_t)sv.y;
      int p2 = atomicAdd(&cnt[dv.z >> 8], 1);
      keys[p2] = ((uint32_t)dv.z << 16) | (uint32_t)sv.z;
      int p3 = atomicAdd(&cnt[dv.w >> 8], 1);
      keys[p3] = ((uint32_t)dv.w << 16) | (uint32_t)sv.w;
    } else {
#pragma unroll
      for (int q = 0; q < 4; q++) {
        int e = e0 + q;
        if (e < cend) {
          int dd, ssrc;
          if (e < E) { dd = ei[E + e]; ssrc = ei[e]; }
          else       { dd = e - E; ssrc = e - E; }
          int p = atomicAdd(&cnt[dd >> 8], 1);
          keys[p] = ((uint32_t)dd << 16) | (uint32_t)ssrc;
        }
      }
    }
  }
}

__global__ void bucket_sort_kernel(const uint32_t* __restrict__ keys,
                                   const int* __restrict__ bucket_base,
                                   int* __restrict__ rowp, int* __restrict__ col) {
  __shared__ int hist[256];
  __shared__ int sc[256];
  __shared__ int ofs[256];
  const int b = blockIdx.x;
  const int t = threadIdx.x;
  hist[t] = 0;
  __syncthreads();
  const int k0 = bucket_base[b], k1 = bucket_base[b + 1];
  for (int i = k0 + t; i < k1; i += 256)
    atomicAdd(&hist[(keys[i] >> 16) & 255], 1);
  __syncthreads();
  const int v = hist[t];
  sc[t] = v;
  __syncthreads();
  for (int off = 1; off < 256; off <<= 1) {
    int tv = (t >= off) ? sc[t - off] : 0;
    __syncthreads();
    sc[t] += tv;
    __syncthreads();
  }
  ofs[t] = k0 + sc[t] - v;
  const int node = b * 256 + t;
  if (node < N) rowp[node] = ofs[t];
  hist[t] = 0;
  __syncthreads();
  for (int i = k0 + t; i < k1; i += 256) {
    uint32_t key = keys[i];
    int loc = (key >> 16) & 255;
    int p = ofs[loc] + atomicAdd(&hist[loc], 1);
    col[p] = (int)(key & 0xFFFFu);
  }
}

// ======== degree-sorted node permutation, DESCENDING (LPT scheduling) ========
// Heavy node-groups land in low block indices -> dispatched first; light blocks
// backfill the tail. Within a wave, the NPW nodes have matched degree.

__global__ void deg_hist_kernel(const int* __restrict__ rowp, int* __restrict__ dh) {
  __shared__ int h[256];
  const int t = threadIdx.x;
  h[t] = 0;
  __syncthreads();
  int i = blockIdx.x * 256 + t;
  if (i < N) {
    int deg = rowp[i + 1] - rowp[i];
    if (deg > 255) deg = 255;
    atomicAdd(&h[deg], 1);
  }
  __syncthreads();
  dh[blockIdx.x * 256 + t] = h[t];
}

__global__ void deg_scan_kernel(const int* __restrict__ dh, int* __restrict__ dbase) {
  __shared__ int sc[256];
  const int d = threadIdx.x;
  int tot = 0;
#pragma unroll 4
  for (int b = 0; b < NBUCK; b++) tot += dh[b * 256 + d];
  sc[d] = tot;
  __syncthreads();
  for (int off = 1; off < 256; off <<= 1) {
    int tv = (d >= off) ? sc[d - off] : 0;
    __syncthreads();
    sc[d] += tv;
    __syncthreads();
  }
  int run = sc[d] - tot;
#pragma unroll 4
  for (int b = 0; b < NBUCK; b++) {
    int v = dh[b * 256 + d];
    dbase[b * 256 + d] = run;
    run += v;
  }
}

__global__ void deg_scatter_kernel(const int* __restrict__ rowp, const int* __restrict__ dbase,
                                   int* __restrict__ perm) {
  __shared__ int cnt[256];
  const int t = threadIdx.x;
  cnt[t] = dbase[blockIdx.x * 256 + t];
  __syncthreads();
  int i = blockIdx.x * 256 + t;
  if (i < N) {
    int deg = rowp[i + 1] - rowp[i];
    if (deg > 255) deg = 255;
    int p = atomicAdd(&cnt[deg], 1);
    perm[N - 1 - p] = i;            // descending degree
  }
}

// ------- union prep: x -> bf16 pairs, and W1..W4 -> bf16 W^T -------

constexpr int TOB_N2 = N * (F / 2);                       // 6.4M u32
constexpr int T1 = 96 * 256, T2 = 96 * 96, T3 = 96 * 96, T4 = 48 * 96;
constexpr int CVT_T = T1 + T2 + T3 + T4;

__global__ void prep_kernel(const float* __restrict__ x, uint32_t* __restrict__ xB,
                            const float* __restrict__ W1, const float* __restrict__ W2,
                            const float* __restrict__ W3, const float* __restrict__ W4,
                            uint16_t* __restrict__ WT1, uint16_t* __restrict__ WT2,
                            uint16_t* __restrict__ WT3, uint16_t* __restrict__ WT4) {
  int t = blockIdx.x * 256 + threadIdx.x;
  if (t < TOB_N2) {
    float2 v = reinterpret_cast<const float2*>(x)[t];
    xB[t] = (f2bf(v.y) << 16) | f2bf(v.x);
    return;
  }
  t -= TOB_N2;
  if (t < T1) {
    int n = t / 256, k = t % 256;
    WT1[t] = (uint16_t)f2bf(W1[(size_t)k * 96 + n]);
  } else if (t < T1 + T2) {
    int u = t - T1; int n = u / 96, k = u % 96;
    WT2[u] = (uint16_t)f2bf(W2[(size_t)k * 96 + n]);
  } else if (t < T1 + T2 + T3) {
    int u = t - T1 - T2; int n = u / 96, k = u % 96;
    WT3[u] = (uint16_t)f2bf(W3[(size_t)k * 96 + n]);
  } else if (t < CVT_T) {
    int u = t - T1 - T2 - T3; int n = u / 96, k = u % 96;
    WT4[u] = (n < K) ? (uint16_t)f2bf(W4[(size_t)k * K + n]) : (uint16_t)0;
  }
}

// ---- fused MFMA GEMM + fp8-record pack (hidden layers, NCOLS=96) ----

template <int KD>
__launch_bounds__(256)
__global__ void gemm_pack_kernel(const uint32_t* __restrict__ A,
                                 const uint16_t* __restrict__ WT,
                                 const float* __restrict__ as_,
                                 const float* __restrict__ ad_,
                                 uint32_t* __restrict__ recs,
                                 float* __restrict__ aldP) {
  constexpr int KU = KD / 2;
  __shared__ float lds[64][97];
  const int wave = threadIdx.x >> 6;
  const int lane = threadIdx.x & 63;
  const int r = lane & 15, g = lane >> 4;
  const int m0 = (blockIdx.x * 4 + wave) * 16;
  int rowA = m0 + r;
  if (rowA > N - 1) rowA = N - 1;
  const uint32_t* arow = A + (size_t)rowA * KU + g * 4;
  const uint32_t* wt32 = reinterpret_cast<const uint32_t*>(WT);

  f32x4 acc[6];
#pragma unroll
  for (int nt = 0; nt < 6; nt++) acc[nt] = (f32x4){0.f, 0.f, 0.f, 0.f};

#pragma unroll
  for (int ks = 0; ks < KD / 32; ks++) {
    short8 av = *reinterpret_cast<const short8*>(arow + ks * 16);
#pragma unroll
    for (int nt = 0; nt < 6; nt++) {
      short8 bv = *reinterpret_cast<const short8*>(
          wt32 + (size_t)(nt * 16 + r) * KU + ks * 16 + g * 4);
      acc[nt] = __builtin_amdgcn_mfma_f32_16x16x32_bf16(av, bv, acc[nt], 0, 0, 0);
    }
  }

  const int lr0 = wave * 16 + g * 4;
#pragma unroll
  for (int nt = 0; nt < 6; nt++) {
#pragma unroll
    for (int t = 0; t < 4; t++) lds[lr0 + t][nt * 16 + r] = acc[nt][t];
  }
  __syncthreads();

  const int row = threadIdx.x >> 2;   // 0..63
  const int q = threadIdx.x & 3;      // 0..3
  const int grow = blockIdx.x * 64 + row;
  if (grow < N) {
    const float* lr = lds[row];
    uint32_t* rp = recs + (size_t)grow * 32;
#pragma unroll
    for (int w = 0; w < 6; w++) {
      const int c0 = q * 24 + w * 4;
      uint32_t wv = 0;
      wv = (uint32_t)__builtin_amdgcn_cvt_pk_fp8_f32(lr[c0], lr[c0 + 1], (int)wv, false);
      wv = (uint32_t)__builtin_amdgcn_cvt_pk_fp8_f32(lr[c0 + 2], lr[c0 + 3], (int)wv, true);
      rp[q * 6 + w] = wv;
    }
#pragma unroll
    for (int i = 0; i < 3; i++) {
      const int d = q * 3 + i;        // 12 dots: (head, s/d)
      const int hh = d >> 1;
      const float* av = (d & 1) ? ad_ : as_;
      float s = 0.f;
#pragma unroll
      for (int c = 0; c < 16; c++) s += lr[hh * 16 + c] * av[hh * 16 + c];
      if (d & 1) aldP[(size_t)grow * 8 + hh] = s;
      else       rp[24 + hh] = __float_as_uint(s);
    }
  }
}

// ---- fused MFMA GEMM + pack for layer 4 (KD=96 -> 40 ch, 64B records) ----

__launch_bounds__(256)
__global__ void gemm_pack4_kernel(const uint32_t* __restrict__ A,
                                  const uint16_t* __restrict__ WT,
                                  const float* __restrict__ as_,
                                  const float* __restrict__ ad_,
                                  uint32_t* __restrict__ recs4,
                                  float* __restrict__ ald4) {
  constexpr int KU = 48;              // 96 bf16 = 48 u32 per row
  __shared__ float lds[64][49];
  const int wave = threadIdx.x >> 6;
  const int lane = threadIdx.x & 63;
  const int r = lane & 15, g = lane >> 4;
  const int m0 = (blockIdx.x * 4 + wave) * 16;
  int rowA = m0 + r;
  if (rowA > N - 1) rowA = N - 1;
  const uint32_t* arow = A + (size_t)rowA * KU + g * 4;
  const uint32_t* wt32 = reinterpret_cast<const uint32_t*>(WT);

  f32x4 acc[3];
#pragma unroll
  for (int nt = 0; nt < 3; nt++) acc[nt] = (f32x4){0.f, 0.f, 0.f, 0.f};

#pragma unroll
  for (int ks = 0; ks < 3; ks++) {
    short8 av = *reinterpret_cast<const short8*>(arow + ks * 16);
#pragma unroll
    for (int nt = 0; nt < 3; nt++) {
      short8 bv = *reinterpret_cast<const short8*>(
          wt32 + (size_t)(nt * 16 + r) * KU + ks * 16 + g * 4);
      acc[nt] = __builtin_amdgcn_mfma_f32_16x16x32_bf16(av, bv, acc[nt], 0, 0, 0);
    }
  }

  const int lr0 = wave * 16 + g * 4;
#pragma unroll
  for (int nt = 0; nt < 3; nt++) {
#pragma unroll
    for (int t = 0; t < 4; t++) lds[lr0 + t][nt * 16 + r] = acc[nt][t];
  }
  __syncthreads();

  if (threadIdx.x < 64) {
    const int row = threadIdx.x;
    const int grow = blockIdx.x * 64 + row;
    if (grow < N) {
      const float* lr = lds[row];
      float ss = 0.f, dd = 0.f;
#pragma unroll
      for (int c = 0; c < 40; c++) {
        ss += lr[c] * as_[c];
        dd += lr[c] * ad_[c];
      }
      uint32_t* rp = recs4 + (size_t)grow * 16;
#pragma unroll
      for (int q = 0; q < 10; q++) {
        uint32_t w = 0;
        w = (uint32_t)__builtin_amdgcn_cvt_pk_fp8_f32(lr[4 * q], lr[4 * q + 1], (int)w, false);
        w = (uint32_t)__builtin_amdgcn_cvt_pk_fp8_f32(lr[4 * q + 2], lr[4 * q + 3], (int)w, true);
        rp[q] = w;
      }
      rp[10] = __float_as_uint(ss);
      ald4[grow] = dd;
    }
  }
}

// ------- degree-sorted (descending) multi-node-per-wave flash aggregate -------
// LPN=12 lanes/node (8 fp8 ch each), NPW=5 nodes/wave, split halves for 2x MLP.

template <int LPN, int NPW, int REC32, int ALSW, int HDIV, int PAD, bool LSM>
__launch_bounds__(256)
__global__ void flash_agg5_kernel(const uint32_t* __restrict__ recs,
                                  const int* __restrict__ rowp,
                                  const int* __restrict__ col,
                                  const int* __restrict__ perm,
                                  const float* __restrict__ aldP,
                                  const float* __restrict__ bias,
                                  uint4* __restrict__ outB4,
                                  float* __restrict__ outF32) {
  const int lane = threadIdx.x & 63;
  const int wave = threadIdx.x >> 6;
  int g = lane / LPN;
  const int li = lane - g * LPN;
  if (g > NPW - 1) g = NPW - 1;
  int idx = (blockIdx.x * 4 + wave) * NPW + g;
  if (idx > N - 1) idx = N - 1;
  const int n = perm[idx];
  const int hh = li / HDIV;
  const float aldv = aldP[(size_t)n * PAD + hh];
  const int b0 = rowp[n];
  const int deg = rowp[n + 1] - b0;
  const int d1 = deg >> 1;        // half A: [0,d1)
  const int d2 = deg - d1;        // half B: [d1,deg)

  int km = d2;
#pragma unroll
  for (int off = 32; off > 0; off >>= 1) {
    int o = __shfl_xor(km, off);
    km = (o > km) ? o : km;
  }

  float a0 = 0.f, a1 = 0.f, a2 = 0.f, a3 = 0.f;
  float a4 = 0.f, a5 = 0.f, a6 = 0.f, a7 = 0.f;
  float b0f = 0.f, b1f = 0.f, b2f = 0.f, b3f = 0.f;
  float b4f = 0.f, b5f = 0.f, b6f = 0.f, b7f = 0.f;
  float ssA = 0.f, ssB = 0.f;

#pragma unroll 2
  for (int k = 0; k < km; k++) {
    const bool vA = (k < d1);
    const bool vB = (k < d2);
    const int jA = b0 + (vA ? k : 0);
    const int jB = b0 + d1 + (vB ? k : 0);
    const int srcA = col[jA];
    const int srcB = col[jB];
    const uint32_t* recA = recs + (size_t)srcA * REC32;
    const uint32_t* recB = recs + (size_t)srcB * REC32;
    uint2 uA = *reinterpret_cast<const uint2*>(recA + 2 * li);
    uint2 uB = *reinterpret_cast<const uint2*>(recB + 2 * li);
    float lA = __uint_as_float(recA[ALSW + hh]);
    float lB = __uint_as_float(recB[ALSW + hh]);
    float eA = lA + aldv; eA = fmaxf(eA, 0.2f * eA);
    float eB = lB + aldv; eB = fmaxf(eB, 0.2f * eB);
    float pA = __expf(eA); pA = vA ? pA : 0.f;
    float pB = __expf(eB); pB = vB ? pB : 0.f;
    f32x2 cA0 = __builtin_amdgcn_cvt_pk_f32_fp8((int)uA.x, false);
    f32x2 cA1 = __builtin_amdgcn_cvt_pk_f32_fp8((int)uA.x, true);
    f32x2 cA2 = __builtin_amdgcn_cvt_pk_f32_fp8((int)uA.y, false);
    f32x2 cA3 = __builtin_amdgcn_cvt_pk_f32_fp8((int)uA.y, true);
    f32x2 cB0 = __builtin_amdgcn_cvt_pk_f32_fp8((int)uB.x, false);
    f32x2 cB1 = __builtin_amdgcn_cvt_pk_f32_fp8((int)uB.x, true);
    f32x2 cB2 = __builtin_amdgcn_cvt_pk_f32_fp8((int)uB.y, false);
    f32x2 cB3 = __builtin_amdgcn_cvt_pk_f32_fp8((int)uB.y, true);
    a0 += pA * cA0.x; a1 += pA * cA0.y;
    a2 += pA * cA1.x; a3 += pA * cA1.y;
    a4 += pA * cA2.x; a5 += pA * cA2.y;
    a6 += pA * cA3.x; a7 += pA * cA3.y;
    ssA += pA;
    b0f += pB * cB0.x; b1f += pB * cB0.y;
    b2f += pB * cB1.x; b3f += pB * cB1.y;
    b4f += pB * cB2.x; b5f += pB * cB2.y;
    b6f += pB * cB3.x; b7f += pB * cB3.y;
    ssB += pB;
  }

  a0 += b0f; a1 += b1f; a2 += b2f; a3 += b3f;
  a4 += b4f; a5 += b5f; a6 += b6f; a7 += b7f;
  float inv = 1.f / (ssA + ssB + 1e-16f);

  if (!LSM) {
    float o0 = fmaxf(a0 * inv + bias[8 * li + 0], 0.f);
    float o1 = fmaxf(a1 * inv + bias[8 * li + 1], 0.f);
    float o2 = fmaxf(a2 * inv + bias[8 * li + 2], 0.f);
    float o3 = fmaxf(a3 * inv + bias[8 * li + 3], 0.f);
    float o4 = fmaxf(a4 * inv + bias[8 * li + 4], 0.f);
    float o5 = fmaxf(a5 * inv + bias[8 * li + 5], 0.f);
    float o6 = fmaxf(a6 * inv + bias[8 * li + 6], 0.f);
    float o7 = fmaxf(a7 * inv + bias[8 * li + 7], 0.f);
    uint4 w;
    w.x = (f2bf(o1) << 16) | f2bf(o0);
    w.y = (f2bf(o3) << 16) | f2bf(o2);
    w.z = (f2bf(o5) << 16) | f2bf(o4);
    w.w = (f2bf(o7) << 16) | f2bf(o6);
    outB4[(size_t)n * LPN + li] = w;
  } else {
    bool vl = (li < 5);
    float v0 = vl ? a0 * inv + bias[8 * li + 0] : -1e30f;
    float v1 = vl ? a1 * inv + bias[8 * li + 1] : -1e30f;
    float v2 = vl ? a2 * inv + bias[8 * li + 2] : -1e30f;
    float v3 = vl ? a3 * inv + bias[8 * li + 3] : -1e30f;
    float v4 = vl ? a4 * inv + bias[8 * li + 4] : -1e30f;
    float v5 = vl ? a5 * inv + bias[8 * li + 5] : -1e30f;
    float v6 = vl ? a6 * inv + bias[8 * li + 6] : -1e30f;
    float v7 = vl ? a7 * inv + bias[8 * li + 7] : -1e30f;
    float mx = fmaxf(fmaxf(fmaxf(v0, v1), fmaxf(v2, v3)),
                     fmaxf(fmaxf(v4, v5), fmaxf(v6, v7)));
#pragma unroll
    for (int off = 1; off < 8; off <<= 1) mx = fmaxf(mx, __shfl_xor(mx, off));
    float es = 0.f;
    if (vl)
      es = __expf(v0 - mx) + __expf(v1 - mx) + __expf(v2 - mx) + __expf(v3 - mx) +
           __expf(v4 - mx) + __expf(v5 - mx) + __expf(v6 - mx) + __expf(v7 - mx);
#pragma unroll
    for (int off = 1; off < 8; off <<= 1) es += __shfl_xor(es, off);
    float lse = mx + __logf(es);
    if (vl) {
      float* op = outF32 + (size_t)n * K + li * 8;
      float4 w0 = make_float4(v0 - lse, v1 - lse, v2 - lse, v3 - lse);
      float4 w1 = make_float4(v4 - lse, v5 - lse, v6 - lse, v7 - lse);
      *reinterpret_cast<float4*>(op) = w0;
      *reinterpret_cast<float4*>(op + 4) = w1;
    }
  }
}

inline int cdiv(int a, int b) { return (a + b - 1) / b; }

}  // namespace

extern "C" void kernel_launch(void* const* d_in, const int* in_sizes, int n_in,
                              void* d_out, int out_size, void* d_ws, size_t ws_size,
                              hipStream_t stream) {
  (void)in_sizes; (void)n_in; (void)out_size; (void)ws_size;
  const float* x   = (const float*)d_in[0];
  const int*   ei  = (const int*)d_in[1];
  const float* W1  = (const float*)d_in[2];
  const float* a1s = (const float*)d_in[3];
  const float* a1d = (const float*)d_in[4];
  const float* b1  = (const float*)d_in[5];
  const float* W2  = (const float*)d_in[6];
  const float* a2s = (const float*)d_in[7];
  const float* a2d = (const float*)d_in[8];
  const float* b2  = (const float*)d_in[9];
  const float* W3  = (const float*)d_in[10];
  const float* a3s = (const float*)d_in[11];
  const float* a3d = (const float*)d_in[12];
  const float* b3  = (const float*)d_in[13];
  const float* W4  = (const float*)d_in[14];
  const float* a4s = (const float*)d_in[15];
  const float* a4d = (const float*)d_in[16];
  const float* b4  = (const float*)d_in[17];
  float* out = (float*)d_out;

  char* ws = (char*)d_ws;
  size_t off = 0;
  auto alloc = [&](size_t bytes) {
    void* p = ws + off;
    off = (off + bytes + 255) & ~(size_t)255;
    return p;
  };
  int*      hist  = (int*)alloc((size_t)HBLK * 256 * 4);
  int*      basep = (int*)alloc((size_t)HBLK * 256 * 4);
  int*      bbase = (int*)alloc((size_t)257 * 4);
  int*      rowp  = (int*)alloc((size_t)(N + 1) * 4);
  uint32_t* keys  = (uint32_t*)alloc((size_t)ET * 4);
  int*      col   = (int*)alloc((size_t)ET * 4);
  int*      perm  = (int*)alloc((size_t)N * 4);
  uint32_t* xB    = (uint32_t*)alloc((size_t)N * (F / 2) * 4);
  uint16_t* WT1   = (uint16_t*)alloc((size_t)96 * 256 * 2);
  uint16_t* WT2   = (uint16_t*)alloc((size_t)96 * 96 * 2);
  uint16_t* WT3   = (uint16_t*)alloc((size_t)96 * 96 * 2);
  uint16_t* WT4   = (uint16_t*)alloc((size_t)48 * 96 * 2);
  uint32_t* actB  = (uint32_t*)alloc((size_t)N * (HC / 2) * 4);
  uint32_t* recs  = (uint32_t*)alloc((size_t)N * 32 * 4);   // 128B records (fp8 h + als)
  uint32_t* recs4 = (uint32_t*)alloc((size_t)N * 16 * 4);   // 64B records (L4)
  float*    aldP  = (float*)alloc((size_t)N * 8 * 4);

  // ---- build CSR: LDS counting sort, zero global atomics ----
  coarse_hist_kernel<<<HBLK, 256, 0, stream>>>(ei, hist);
  coarse_scan_kernel<<<1, 256, 0, stream>>>(hist, basep, bbase, rowp);
  coarse_scatter_kernel<<<HBLK, 256, 0, stream>>>(ei, basep, keys);
  bucket_sort_kernel<<<NBUCK, 256, 0, stream>>>(keys, bbase, rowp, col);

  // ---- degree-sorted node permutation, descending (reuses hist/basep) ----
  deg_hist_kernel<<<NBUCK, 256, 0, stream>>>(rowp, hist);
  deg_scan_kernel<<<1, 256, 0, stream>>>(hist, basep);
  deg_scatter_kernel<<<NBUCK, 256, 0, stream>>>(rowp, basep, perm);

  // ---- dtype prep (x -> bf16, W -> W^T bf16) ----
  prep_kernel<<<cdiv(TOB_N2 + CVT_T, 256), 256, 0, stream>>>(
      x, xB, W1, W2, W3, W4, WT1, WT2, WT3, WT4);

  const int gG   = cdiv(N, 64);     // GEMM: 4 waves x 16 rows per block
  const int gA96 = cdiv(N, 20);     // agg L1-3: 4 waves x 5 nodes
  const int gA40 = cdiv(N, 32);     // agg L4:   4 waves x 8 nodes

  // ---- layer 1 ----
  gemm_pack_kernel<F><<<gG, 256, 0, stream>>>(xB, WT1, a1s, a1d, recs, aldP);
  flash_agg5_kernel<12, 5, 32, 24, 2, 8, false><<<gA96, 256, 0, stream>>>(
      recs, rowp, col, perm, aldP, b1, (uint4*)actB, nullptr);

  // ---- layer 2 ----
  gemm_pack_kernel<HC><<<gG, 256, 0, stream>>>(actB, WT2, a2s, a2d, recs, aldP);
  flash_agg5_kernel<12, 5, 32, 24, 2, 8, false><<<gA96, 256, 0, stream>>>(
      recs, rowp, col, perm, aldP, b2, (uint4*)actB, nullptr);

  // ---- layer 3 ----
  gemm_pack_kernel<HC><<<gG, 256, 0, stream>>>(actB, WT3, a3s, a3d, recs, aldP);
  flash_agg5_kernel<12, 5, 32, 24, 2, 8, false><<<gA96, 256, 0, stream>>>(
      recs, rowp, col, perm, aldP, b3, (uint4*)actB, nullptr);

  // ---- layer 4: fused GEMM+pack, aggregate + log_softmax ----
  gemm_pack4_kernel<<<gG, 256, 0, stream>>>(actB, WT4, a4s, a4d, recs4, aldP);
  flash_agg5_kernel<8, 8, 16, 10, 16, 1, true><<<gA40, 256, 0, stream>>>(
      recs4, rowp, col, perm, aldP, b4, nullptr, out);
}

// Round 13
// 288.080 us; speedup vs baseline: 1.1026x; 1.0044x over previous
//
#include <hip/hip_runtime.h>
#include <cstdint>
#include <cstddef>

namespace {

constexpr int N  = 50000;
constexpr int E  = 1600000;
constexpr int ET = E + N;          // edges + self loops
constexpr int F  = 256;
constexpr int H  = 6;
constexpr int C  = 16;
constexpr int HC = H * C;          // 96
constexpr int K  = 40;
constexpr int NBUCK = (N + 255) / 256;        // 196 coarse buckets (dst>>8)
constexpr int EPB2  = 8192;                   // edges per block in CSR passes
constexpr int HBLK  = (ET + EPB2 - 1) / EPB2; // 202

typedef __attribute__((ext_vector_type(8))) short short8;
typedef __attribute__((ext_vector_type(4))) float f32x4;
typedef __attribute__((ext_vector_type(2))) float f32x2;

__device__ inline uint32_t f2bf(float f) {  // RNE fp32 -> bf16
  uint32_t u = __float_as_uint(f);
  return (u + 0x7FFFu + ((u >> 16) & 1u)) >> 16;
}
__device__ inline float bflo(uint32_t u) { return __uint_as_float(u << 16); }
__device__ inline float bfhi(uint32_t u) { return __uint_as_float(u & 0xFFFF0000u); }

// ======== CSR via two-level LDS counting sort (NO global atomics) ========

__global__ void coarse_hist_kernel(const int* __restrict__ ei, int* __restrict__ hist) {
  __shared__ int h[256];
  const int t = threadIdx.x;
  h[t] = 0;
  __syncthreads();
  const int cbase = blockIdx.x * EPB2;
  const int cend = (cbase + EPB2 < ET) ? (cbase + EPB2) : ET;
  for (int e0 = cbase + t * 4; e0 < cend; e0 += 1024) {
    if (e0 + 3 < E && e0 + 3 < cend) {
      int4 dv = *reinterpret_cast<const int4*>(ei + E + e0);
      atomicAdd(&h[dv.x >> 8], 1);
      atomicAdd(&h[dv.y >> 8], 1);
      atomicAdd(&h[dv.z >> 8], 1);
      atomicAdd(&h[dv.w >> 8], 1);
    } else {
#pragma unroll
      for (int q = 0; q < 4; q++) {
        int e = e0 + q;
        if (e < cend) {
          int dd = (e < E) ? ei[E + e] : (e - E);
          atomicAdd(&h[dd >> 8], 1);
        }
      }
    }
  }
  __syncthreads();
  hist[blockIdx.x * 256 + t] = h[t];
}

__global__ void coarse_scan_kernel(const int* __restrict__ hist, int* __restrict__ base,
                                   int* __restrict__ bucket_base, int* __restrict__ rowp) {
  __shared__ int sc[256];
  const int d = threadIdx.x;
  int tot = 0;
#pragma unroll 4
  for (int b = 0; b < HBLK; b++) tot += hist[b * 256 + d];
  sc[d] = tot;
  __syncthreads();
  for (int off = 1; off < 256; off <<= 1) {
    int tv = (d >= off) ? sc[d - off] : 0;
    __syncthreads();
    sc[d] += tv;
    __syncthreads();
  }
  const int excl = sc[d] - tot;
  bucket_base[d] = excl;
  if (d == 255) {
    bucket_base[256] = sc[255];
    rowp[N] = sc[255];   // == ET
  }
  int run = excl;
#pragma unroll 4
  for (int b = 0; b < HBLK; b++) {
    int v = hist[b * 256 + d];
    base[b * 256 + d] = run;
    run += v;
  }
}

__global__ void coarse_scatter_kernel(const int* __restrict__ ei, const int* __restrict__ base,
                                      uint32_t* __restrict__ keys) {
  __shared__ int cnt[256];
  const int t = threadIdx.x;
  cnt[t] = base[blockIdx.x * 256 + t];
  __syncthreads();
  const int cbase = blockIdx.x * EPB2;
  const int cend = (cbase + EPB2 < ET) ? (cbase + EPB2) : ET;
  for (int e0 = cbase + t * 4; e0 < cend; e0 += 1024) {
    if (e0 + 3 < E && e0 + 3 < cend) {
      int4 dv = *reinterpret_cast<const int4*>(ei + E + e0);
      int4 sv = *reinterpret_cast<const int4*>(ei + e0);
      int p0 = atomicAdd(&cnt[dv.x >> 8], 1);
      keys[p0] = ((uint32_t)dv.x << 16) | (uint32_t)sv.x;
      int p1 = atomicAdd(&cnt[dv.y >> 8], 1);
      keys[p1] = ((uint32_t)dv.y << 16) | (uint32_t)sv.y;
      int p2 = atomicAdd(&cnt[dv.z >> 8], 1);
      keys[p2] = ((uint32_t)dv.z << 16) | (uint32_t)sv.z;
      int p3 = atomicAdd(&cnt[dv.w >> 8], 1);
      keys[p3] = ((uint32_t)dv.w << 16) | (uint32_t)sv.w;
    } else {
#pragma unroll
      for (int q = 0; q < 4; q++) {
        int e = e0 + q;
        if (e < cend) {
          int dd, ssrc;
          if (e < E) { dd = ei[E + e]; ssrc = ei[e]; }
          else       { dd = e - E; ssrc = e - E; }
          int p = atomicAdd(&cnt[dd >> 8], 1);
          keys[p] = ((uint32_t)dd << 16) | (uint32_t)ssrc;
        }
      }
    }
  }
}

__global__ void bucket_sort_kernel(const uint32_t* __restrict__ keys,
                                   const int* __restrict__ bucket_base,
                                   int* __restrict__ rowp, int* __restrict__ col) {
  __shared__ int hist[256];
  __shared__ int sc[256];
  __shared__ int ofs[256];
  const int b = blockIdx.x;
  const int t = threadIdx.x;
  hist[t] = 0;
  __syncthreads();
  const int k0 = bucket_base[b], k1 = bucket_base[b + 1];
  for (int i = k0 + t; i < k1; i += 256)
    atomicAdd(&hist[(keys[i] >> 16) & 255], 1);
  __syncthreads();
  const int v = hist[t];
  sc[t] = v;
  __syncthreads();
  for (int off = 1; off < 256; off <<= 1) {
    int tv = (t >= off) ? sc[t - off] : 0;
    __syncthreads();
    sc[t] += tv;
    __syncthreads();
  }
  ofs[t] = k0 + sc[t] - v;
  const int node = b * 256 + t;
  if (node < N) rowp[node] = ofs[t];
  hist[t] = 0;
  __syncthreads();
  for (int i = k0 + t; i < k1; i += 256) {
    uint32_t key = keys[i];
    int loc = (key >> 16) & 255;
    int p = ofs[loc] + atomicAdd(&hist[loc], 1);
    col[p] = (int)(key & 0xFFFFu);
  }
}

// ======== degree-sorted node permutation, DESCENDING (LPT scheduling) ========

__global__ void deg_hist_kernel(const int* __restrict__ rowp, int* __restrict__ dh) {
  __shared__ int h[256];
  const int t = threadIdx.x;
  h[t] = 0;
  __syncthreads();
  int i = blockIdx.x * 256 + t;
  if (i < N) {
    int deg = rowp[i + 1] - rowp[i];
    if (deg > 255) deg = 255;
    atomicAdd(&h[deg], 1);
  }
  __syncthreads();
  dh[blockIdx.x * 256 + t] = h[t];
}

__global__ void deg_scan_kernel(const int* __restrict__ dh, int* __restrict__ dbase) {
  __shared__ int sc[256];
  const int d = threadIdx.x;
  int tot = 0;
#pragma unroll 4
  for (int b = 0; b < NBUCK; b++) tot += dh[b * 256 + d];
  sc[d] = tot;
  __syncthreads();
  for (int off = 1; off < 256; off <<= 1) {
    int tv = (d >= off) ? sc[d - off] : 0;
    __syncthreads();
    sc[d] += tv;
    __syncthreads();
  }
  int run = sc[d] - tot;
#pragma unroll 4
  for (int b = 0; b < NBUCK; b++) {
    int v = dh[b * 256 + d];
    dbase[b * 256 + d] = run;
    run += v;
  }
}

__global__ void deg_scatter_kernel(const int* __restrict__ rowp, const int* __restrict__ dbase,
                                   int* __restrict__ perm) {
  __shared__ int cnt[256];
  const int t = threadIdx.x;
  cnt[t] = dbase[blockIdx.x * 256 + t];
  __syncthreads();
  int i = blockIdx.x * 256 + t;
  if (i < N) {
    int deg = rowp[i + 1] - rowp[i];
    if (deg > 255) deg = 255;
    int p = atomicAdd(&cnt[deg], 1);
    perm[N - 1 - p] = i;            // descending degree -> LPT dispatch
  }
}

// ------- union prep: x -> bf16 pairs, and W1..W4 -> bf16 W^T -------

constexpr int TOB_N2 = N * (F / 2);                       // 6.4M u32
constexpr int T1 = 96 * 256, T2 = 96 * 96, T3 = 96 * 96, T4 = 48 * 96;
constexpr int CVT_T = T1 + T2 + T3 + T4;

__global__ void prep_kernel(const float* __restrict__ x, uint32_t* __restrict__ xB,
                            const float* __restrict__ W1, const float* __restrict__ W2,
                            const float* __restrict__ W3, const float* __restrict__ W4,
                            uint16_t* __restrict__ WT1, uint16_t* __restrict__ WT2,
                            uint16_t* __restrict__ WT3, uint16_t* __restrict__ WT4) {
  int t = blockIdx.x * 256 + threadIdx.x;
  if (t < TOB_N2) {
    float2 v = reinterpret_cast<const float2*>(x)[t];
    xB[t] = (f2bf(v.y) << 16) | f2bf(v.x);
    return;
  }
  t -= TOB_N2;
  if (t < T1) {
    int n = t / 256, k = t % 256;
    WT1[t] = (uint16_t)f2bf(W1[(size_t)k * 96 + n]);
  } else if (t < T1 + T2) {
    int u = t - T1; int n = u / 96, k = u % 96;
    WT2[u] = (uint16_t)f2bf(W2[(size_t)k * 96 + n]);
  } else if (t < T1 + T2 + T3) {
    int u = t - T1 - T2; int n = u / 96, k = u % 96;
    WT3[u] = (uint16_t)f2bf(W3[(size_t)k * 96 + n]);
  } else if (t < CVT_T) {
    int u = t - T1 - T2 - T3; int n = u / 96, k = u % 96;
    WT4[u] = (n < K) ? (uint16_t)f2bf(W4[(size_t)k * K + n]) : (uint16_t)0;
  }
}

// ---- fused MFMA GEMM + fp8-record pack (hidden layers, NCOLS=96) ----

template <int KD>
__launch_bounds__(256)
__global__ void gemm_pack_kernel(const uint32_t* __restrict__ A,
                                 const uint16_t* __restrict__ WT,
                                 const float* __restrict__ as_,
                                 const float* __restrict__ ad_,
                                 uint32_t* __restrict__ recs,
                                 float* __restrict__ aldP) {
  constexpr int KU = KD / 2;
  __shared__ float lds[64][97];
  const int wave = threadIdx.x >> 6;
  const int lane = threadIdx.x & 63;
  const int r = lane & 15, g = lane >> 4;
  const int m0 = (blockIdx.x * 4 + wave) * 16;
  int rowA = m0 + r;
  if (rowA > N - 1) rowA = N - 1;
  const uint32_t* arow = A + (size_t)rowA * KU + g * 4;
  const uint32_t* wt32 = reinterpret_cast<const uint32_t*>(WT);

  f32x4 acc[6];
#pragma unroll
  for (int nt = 0; nt < 6; nt++) acc[nt] = (f32x4){0.f, 0.f, 0.f, 0.f};

#pragma unroll
  for (int ks = 0; ks < KD / 32; ks++) {
    short8 av = *reinterpret_cast<const short8*>(arow + ks * 16);
#pragma unroll
    for (int nt = 0; nt < 6; nt++) {
      short8 bv = *reinterpret_cast<const short8*>(
          wt32 + (size_t)(nt * 16 + r) * KU + ks * 16 + g * 4);
      acc[nt] = __builtin_amdgcn_mfma_f32_16x16x32_bf16(av, bv, acc[nt], 0, 0, 0);
    }
  }

  const int lr0 = wave * 16 + g * 4;
#pragma unroll
  for (int nt = 0; nt < 6; nt++) {
#pragma unroll
    for (int t = 0; t < 4; t++) lds[lr0 + t][nt * 16 + r] = acc[nt][t];
  }
  __syncthreads();

  const int row = threadIdx.x >> 2;   // 0..63
  const int q = threadIdx.x & 3;      // 0..3
  const int grow = blockIdx.x * 64 + row;
  if (grow < N) {
    const float* lr = lds[row];
    uint32_t* rp = recs + (size_t)grow * 32;
#pragma unroll
    for (int w = 0; w < 6; w++) {
      const int c0 = q * 24 + w * 4;
      uint32_t wv = 0;
      wv = (uint32_t)__builtin_amdgcn_cvt_pk_fp8_f32(lr[c0], lr[c0 + 1], (int)wv, false);
      wv = (uint32_t)__builtin_amdgcn_cvt_pk_fp8_f32(lr[c0 + 2], lr[c0 + 3], (int)wv, true);
      rp[q * 6 + w] = wv;
    }
#pragma unroll
    for (int i = 0; i < 3; i++) {
      const int d = q * 3 + i;        // 12 dots: (head, s/d)
      const int hh = d >> 1;
      const float* av = (d & 1) ? ad_ : as_;
      float s = 0.f;
#pragma unroll
      for (int c = 0; c < 16; c++) s += lr[hh * 16 + c] * av[hh * 16 + c];
      if (d & 1) aldP[(size_t)grow * 8 + hh] = s;
      else       rp[24 + hh] = __float_as_uint(s);
    }
  }
}

// ---- fused MFMA GEMM + pack for layer 4 (KD=96 -> 40 ch, 64B records) ----

__launch_bounds__(256)
__global__ void gemm_pack4_kernel(const uint32_t* __restrict__ A,
                                  const uint16_t* __restrict__ WT,
                                  const float* __restrict__ as_,
                                  const float* __restrict__ ad_,
                                  uint32_t* __restrict__ recs4,
                                  float* __restrict__ ald4) {
  constexpr int KU = 48;              // 96 bf16 = 48 u32 per row
  __shared__ float lds[64][49];
  const int wave = threadIdx.x >> 6;
  const int lane = threadIdx.x & 63;
  const int r = lane & 15, g = lane >> 4;
  const int m0 = (blockIdx.x * 4 + wave) * 16;
  int rowA = m0 + r;
  if (rowA > N - 1) rowA = N - 1;
  const uint32_t* arow = A + (size_t)rowA * KU + g * 4;
  const uint32_t* wt32 = reinterpret_cast<const uint32_t*>(WT);

  f32x4 acc[3];
#pragma unroll
  for (int nt = 0; nt < 3; nt++) acc[nt] = (f32x4){0.f, 0.f, 0.f, 0.f};

#pragma unroll
  for (int ks = 0; ks < 3; ks++) {
    short8 av = *reinterpret_cast<const short8*>(arow + ks * 16);
#pragma unroll
    for (int nt = 0; nt < 3; nt++) {
      short8 bv = *reinterpret_cast<const short8*>(
          wt32 + (size_t)(nt * 16 + r) * KU + ks * 16 + g * 4);
      acc[nt] = __builtin_amdgcn_mfma_f32_16x16x32_bf16(av, bv, acc[nt], 0, 0, 0);
    }
  }

  const int lr0 = wave * 16 + g * 4;
#pragma unroll
  for (int nt = 0; nt < 3; nt++) {
#pragma unroll
    for (int t = 0; t < 4; t++) lds[lr0 + t][nt * 16 + r] = acc[nt][t];
  }
  __syncthreads();

  if (threadIdx.x < 64) {
    const int row = threadIdx.x;
    const int grow = blockIdx.x * 64 + row;
    if (grow < N) {
      const float* lr = lds[row];
      float ss = 0.f, dd = 0.f;
#pragma unroll
      for (int c = 0; c < 40; c++) {
        ss += lr[c] * as_[c];
        dd += lr[c] * ad_[c];
      }
      uint32_t* rp = recs4 + (size_t)grow * 16;
#pragma unroll
      for (int q = 0; q < 10; q++) {
        uint32_t w = 0;
        w = (uint32_t)__builtin_amdgcn_cvt_pk_fp8_f32(lr[4 * q], lr[4 * q + 1], (int)w, false);
        w = (uint32_t)__builtin_amdgcn_cvt_pk_fp8_f32(lr[4 * q + 2], lr[4 * q + 3], (int)w, true);
        rp[q] = w;
      }
      rp[10] = __float_as_uint(ss);
      ald4[grow] = dd;
    }
  }
}

// ------- degree-sorted (descending) multi-node-per-wave flash aggregate -------
// LPN lanes/node, NPW nodes/wave, split halves; unroll 4 => 8 record fetches
// in flight per lane. LPT permutation keeps per-wave trip counts matched.

template <int LPN, int NPW, int REC32, int ALSW, int HDIV, int PAD, bool LSM>
__launch_bounds__(256)
__global__ void flash_agg5_kernel(const uint32_t* __restrict__ recs,
                                  const int* __restrict__ rowp,
                                  const int* __restrict__ col,
                                  const int* __restrict__ perm,
                                  const float* __restrict__ aldP,
                                  const float* __restrict__ bias,
                                  uint4* __restrict__ outB4,
                                  float* __restrict__ outF32) {
  const int lane = threadIdx.x & 63;
  const int wave = threadIdx.x >> 6;
  int g = lane / LPN;
  const int li = lane - g * LPN;
  if (g > NPW - 1) g = NPW - 1;
  int idx = (blockIdx.x * 4 + wave) * NPW + g;
  if (idx > N - 1) idx = N - 1;
  const int n = perm[idx];
  const int hh = li / HDIV;
  const float aldv = aldP[(size_t)n * PAD + hh];
  const int b0 = rowp[n];
  const int deg = rowp[n + 1] - b0;
  const int d1 = deg >> 1;        // half A: [0,d1)
  const int d2 = deg - d1;        // half B: [d1,deg)

  int km = d2;
#pragma unroll
  for (int off = 32; off > 0; off >>= 1) {
    int o = __shfl_xor(km, off);
    km = (o > km) ? o : km;
  }

  float a0 = 0.f, a1 = 0.f, a2 = 0.f, a3 = 0.f;
  float a4 = 0.f, a5 = 0.f, a6 = 0.f, a7 = 0.f;
  float b0f = 0.f, b1f = 0.f, b2f = 0.f, b3f = 0.f;
  float b4f = 0.f, b5f = 0.f, b6f = 0.f, b7f = 0.f;
  float ssA = 0.f, ssB = 0.f;

#pragma unroll 4
  for (int k = 0; k < km; k++) {
    const bool vA = (k < d1);
    const bool vB = (k < d2);
    const int jA = b0 + (vA ? k : 0);
    const int jB = b0 + d1 + (vB ? k : 0);
    const int srcA = col[jA];
    const int srcB = col[jB];
    const uint32_t* recA = recs + (size_t)srcA * REC32;
    const uint32_t* recB = recs + (size_t)srcB * REC32;
    uint2 uA = *reinterpret_cast<const uint2*>(recA + 2 * li);
    uint2 uB = *reinterpret_cast<const uint2*>(recB + 2 * li);
    float lA = __uint_as_float(recA[ALSW + hh]);
    float lB = __uint_as_float(recB[ALSW + hh]);
    float eA = lA + aldv; eA = fmaxf(eA, 0.2f * eA);
    float eB = lB + aldv; eB = fmaxf(eB, 0.2f * eB);
    float pA = __expf(eA); pA = vA ? pA : 0.f;
    float pB = __expf(eB); pB = vB ? pB : 0.f;
    f32x2 cA0 = __builtin_amdgcn_cvt_pk_f32_fp8((int)uA.x, false);
    f32x2 cA1 = __builtin_amdgcn_cvt_pk_f32_fp8((int)uA.x, true);
    f32x2 cA2 = __builtin_amdgcn_cvt_pk_f32_fp8((int)uA.y, false);
    f32x2 cA3 = __builtin_amdgcn_cvt_pk_f32_fp8((int)uA.y, true);
    f32x2 cB0 = __builtin_amdgcn_cvt_pk_f32_fp8((int)uB.x, false);
    f32x2 cB1 = __builtin_amdgcn_cvt_pk_f32_fp8((int)uB.x, true);
    f32x2 cB2 = __builtin_amdgcn_cvt_pk_f32_fp8((int)uB.y, false);
    f32x2 cB3 = __builtin_amdgcn_cvt_pk_f32_fp8((int)uB.y, true);
    a0 += pA * cA0.x; a1 += pA * cA0.y;
    a2 += pA * cA1.x; a3 += pA * cA1.y;
    a4 += pA * cA2.x; a5 += pA * cA2.y;
    a6 += pA * cA3.x; a7 += pA * cA3.y;
    ssA += pA;
    b0f += pB * cB0.x; b1f += pB * cB0.y;
    b2f += pB * cB1.x; b3f += pB * cB1.y;
    b4f += pB * cB2.x; b5f += pB * cB2.y;
    b6f += pB * cB3.x; b7f += pB * cB3.y;
    ssB += pB;
  }

  a0 += b0f; a1 += b1f; a2 += b2f; a3 += b3f;
  a4 += b4f; a5 += b5f; a6 += b6f; a7 += b7f;
  float inv = 1.f / (ssA + ssB + 1e-16f);

  if (!LSM) {
    float o0 = fmaxf(a0 * inv + bias[8 * li + 0], 0.f);
    float o1 = fmaxf(a1 * inv + bias[8 * li + 1], 0.f);
    float o2 = fmaxf(a2 * inv + bias[8 * li + 2], 0.f);
    float o3 = fmaxf(a3 * inv + bias[8 * li + 3], 0.f);
    float o4 = fmaxf(a4 * inv + bias[8 * li + 4], 0.f);
    float o5 = fmaxf(a5 * inv + bias[8 * li + 5], 0.f);
    float o6 = fmaxf(a6 * inv + bias[8 * li + 6], 0.f);
    float o7 = fmaxf(a7 * inv + bias[8 * li + 7], 0.f);
    uint4 w;
    w.x = (f2bf(o1) << 16) | f2bf(o0);
    w.y = (f2bf(o3) << 16) | f2bf(o2);
    w.z = (f2bf(o5) << 16) | f2bf(o4);
    w.w = (f2bf(o7) << 16) | f2bf(o6);
    outB4[(size_t)n * LPN + li] = w;
  } else {
    bool vl = (li < 5);
    float v0 = vl ? a0 * inv + bias[8 * li + 0] : -1e30f;
    float v1 = vl ? a1 * inv + bias[8 * li + 1] : -1e30f;
    float v2 = vl ? a2 * inv + bias[8 * li + 2] : -1e30f;
    float v3 = vl ? a3 * inv + bias[8 * li + 3] : -1e30f;
    float v4 = vl ? a4 * inv + bias[8 * li + 4] : -1e30f;
    float v5 = vl ? a5 * inv + bias[8 * li + 5] : -1e30f;
    float v6 = vl ? a6 * inv + bias[8 * li + 6] : -1e30f;
    float v7 = vl ? a7 * inv + bias[8 * li + 7] : -1e30f;
    float mx = fmaxf(fmaxf(fmaxf(v0, v1), fmaxf(v2, v3)),
                     fmaxf(fmaxf(v4, v5), fmaxf(v6, v7)));
#pragma unroll
    for (int off = 1; off < 8; off <<= 1) mx = fmaxf(mx, __shfl_xor(mx, off));
    float es = 0.f;
    if (vl)
      es = __expf(v0 - mx) + __expf(v1 - mx) + __expf(v2 - mx) + __expf(v3 - mx) +
           __expf(v4 - mx) + __expf(v5 - mx) + __expf(v6 - mx) + __expf(v7 - mx);
#pragma unroll
    for (int off = 1; off < 8; off <<= 1) es += __shfl_xor(es, off);
    float lse = mx + __logf(es);
    if (vl) {
      float* op = outF32 + (size_t)n * K + li * 8;
      float4 w0 = make_float4(v0 - lse, v1 - lse, v2 - lse, v3 - lse);
      float4 w1 = make_float4(v4 - lse, v5 - lse, v6 - lse, v7 - lse);
      *reinterpret_cast<float4*>(op) = w0;
      *reinterpret_cast<float4*>(op + 4) = w1;
    }
  }
}

inline int cdiv(int a, int b) { return (a + b - 1) / b; }

}  // namespace

extern "C" void kernel_launch(void* const* d_in, const int* in_sizes, int n_in,
                              void* d_out, int out_size, void* d_ws, size_t ws_size,
                              hipStream_t stream) {
  (void)in_sizes; (void)n_in; (void)out_size; (void)ws_size;
  const float* x   = (const float*)d_in[0];
  const int*   ei  = (const int*)d_in[1];
  const float* W1  = (const float*)d_in[2];
  const float* a1s = (const float*)d_in[3];
  const float* a1d = (const float*)d_in[4];
  const float* b1  = (const float*)d_in[5];
  const float* W2  = (const float*)d_in[6];
  const float* a2s = (const float*)d_in[7];
  const float* a2d = (const float*)d_in[8];
  const float* b2  = (const float*)d_in[9];
  const float* W3  = (const float*)d_in[10];
  const float* a3s = (const float*)d_in[11];
  const float* a3d = (const float*)d_in[12];
  const float* b3  = (const float*)d_in[13];
  const float* W4  = (const float*)d_in[14];
  const float* a4s = (const float*)d_in[15];
  const float* a4d = (const float*)d_in[16];
  const float* b4  = (const float*)d_in[17];
  float* out = (float*)d_out;

  char* ws = (char*)d_ws;
  size_t off = 0;
  auto alloc = [&](size_t bytes) {
    void* p = ws + off;
    off = (off + bytes + 255) & ~(size_t)255;
    return p;
  };
  int*      hist  = (int*)alloc((size_t)HBLK * 256 * 4);
  int*      basep = (int*)alloc((size_t)HBLK * 256 * 4);
  int*      bbase = (int*)alloc((size_t)257 * 4);
  int*      rowp  = (int*)alloc((size_t)(N + 1) * 4);
  uint32_t* keys  = (uint32_t*)alloc((size_t)ET * 4);
  int*      col   = (int*)alloc((size_t)ET * 4);
  int*      perm  = (int*)alloc((size_t)N * 4);
  uint32_t* xB    = (uint32_t*)alloc((size_t)N * (F / 2) * 4);
  uint16_t* WT1   = (uint16_t*)alloc((size_t)96 * 256 * 2);
  uint16_t* WT2   = (uint16_t*)alloc((size_t)96 * 96 * 2);
  uint16_t* WT3   = (uint16_t*)alloc((size_t)96 * 96 * 2);
  uint16_t* WT4   = (uint16_t*)alloc((size_t)48 * 96 * 2);
  uint32_t* actB  = (uint32_t*)alloc((size_t)N * (HC / 2) * 4);
  uint32_t* recs  = (uint32_t*)alloc((size_t)N * 32 * 4);   // 128B records (fp8 h + als)
  uint32_t* recs4 = (uint32_t*)alloc((size_t)N * 16 * 4);   // 64B records (L4)
  float*    aldP  = (float*)alloc((size_t)N * 8 * 4);

  // ---- build CSR: LDS counting sort, zero global atomics ----
  coarse_hist_kernel<<<HBLK, 256, 0, stream>>>(ei, hist);
  coarse_scan_kernel<<<1, 256, 0, stream>>>(hist, basep, bbase, rowp);
  coarse_scatter_kernel<<<HBLK, 256, 0, stream>>>(ei, basep, keys);
  bucket_sort_kernel<<<NBUCK, 256, 0, stream>>>(keys, bbase, rowp, col);

  // ---- degree-sorted node permutation, descending (reuses hist/basep) ----
  deg_hist_kernel<<<NBUCK, 256, 0, stream>>>(rowp, hist);
  deg_scan_kernel<<<1, 256, 0, stream>>>(hist, basep);
  deg_scatter_kernel<<<NBUCK, 256, 0, stream>>>(rowp, basep, perm);

  // ---- dtype prep (x -> bf16, W -> W^T bf16) ----
  prep_kernel<<<cdiv(TOB_N2 + CVT_T, 256), 256, 0, stream>>>(
      x, xB, W1, W2, W3, W4, WT1, WT2, WT3, WT4);

  const int gG   = cdiv(N, 64);     // GEMM: 4 waves x 16 rows per block
  const int gA96 = cdiv(N, 20);     // agg L1-3: 4 waves x 5 nodes
  const int gA40 = cdiv(N, 32);     // agg L4:   4 waves x 8 nodes

  // ---- layer 1 ----
  gemm_pack_kernel<F><<<gG, 256, 0, stream>>>(xB, WT1, a1s, a1d, recs, aldP);
  flash_agg5_kernel<12, 5, 32, 24, 2, 8, false><<<gA96, 256, 0, stream>>>(
      recs, rowp, col, perm, aldP, b1, (uint4*)actB, nullptr);

  // ---- layer 2 ----
  gemm_pack_kernel<HC><<<gG, 256, 0, stream>>>(actB, WT2, a2s, a2d, recs, aldP);
  flash_agg5_kernel<12, 5, 32, 24, 2, 8, false><<<gA96, 256, 0, stream>>>(
      recs, rowp, col, perm, aldP, b2, (uint4*)actB, nullptr);

  // ---- layer 3 ----
  gemm_pack_kernel<HC><<<gG, 256, 0, stream>>>(actB, WT3, a3s, a3d, recs, aldP);
  flash_agg5_kernel<12, 5, 32, 24, 2, 8, false><<<gA96, 256, 0, stream>>>(
      recs, rowp, col, perm, aldP, b3, (uint4*)actB, nullptr);

  // ---- layer 4: fused GEMM+pack, aggregate + log_softmax ----
  gemm_pack4_kernel<<<gG, 256, 0, stream>>>(actB, WT4, a4s, a4d, recs4, aldP);
  flash_agg5_kernel<8, 8, 16, 10, 16, 1, true><<<gA40, 256, 0, stream>>>(
      recs4, rowp, col, perm, aldP, b4, nullptr, out);
}

// Round 14
// 283.196 us; speedup vs baseline: 1.1216x; 1.0172x over previous
//
#include <hip/hip_runtime.h>
#include <cstdint>
#include <cstddef>

namespace {

constexpr int N  = 50000;
constexpr int E  = 1600000;
constexpr int ET = E + N;          // edges + self loops
constexpr int F  = 256;
constexpr int H  = 6;
constexpr int C  = 16;
constexpr int HC = H * C;          // 96
constexpr int K  = 40;
constexpr int NBUCK = (N + 255) / 256;        // 196 coarse buckets (dst>>8)
constexpr int EPB2  = 8192;                   // edges per block in CSR passes
constexpr int HBLK  = (ET + EPB2 - 1) / EPB2; // 202

typedef __attribute__((ext_vector_type(8))) short short8;
typedef __attribute__((ext_vector_type(4))) float f32x4;
typedef __attribute__((ext_vector_type(2))) float f32x2;

__device__ inline uint32_t f2bf(float f) {  // RNE fp32 -> bf16
  uint32_t u = __float_as_uint(f);
  return (u + 0x7FFFu + ((u >> 16) & 1u)) >> 16;
}
__device__ inline float bflo(uint32_t u) { return __uint_as_float(u << 16); }
__device__ inline float bfhi(uint32_t u) { return __uint_as_float(u & 0xFFFF0000u); }

// ======== CSR via two-level LDS counting sort (NO global atomics) ========

__global__ void coarse_hist_kernel(const int* __restrict__ ei, int* __restrict__ hist) {
  __shared__ int h[256];
  const int t = threadIdx.x;
  h[t] = 0;
  __syncthreads();
  const int cbase = blockIdx.x * EPB2;
  const int cend = (cbase + EPB2 < ET) ? (cbase + EPB2) : ET;
  for (int e0 = cbase + t * 4; e0 < cend; e0 += 1024) {
    if (e0 + 3 < E && e0 + 3 < cend) {
      int4 dv = *reinterpret_cast<const int4*>(ei + E + e0);
      atomicAdd(&h[dv.x >> 8], 1);
      atomicAdd(&h[dv.y >> 8], 1);
      atomicAdd(&h[dv.z >> 8], 1);
      atomicAdd(&h[dv.w >> 8], 1);
    } else {
#pragma unroll
      for (int q = 0; q < 4; q++) {
        int e = e0 + q;
        if (e < cend) {
          int dd = (e < E) ? ei[E + e] : (e - E);
          atomicAdd(&h[dd >> 8], 1);
        }
      }
    }
  }
  __syncthreads();
  hist[blockIdx.x * 256 + t] = h[t];
}

__global__ void coarse_scan_kernel(const int* __restrict__ hist, int* __restrict__ base,
                                   int* __restrict__ bucket_base, int* __restrict__ rowp) {
  __shared__ int sc[256];
  const int d = threadIdx.x;
  int tot = 0;
#pragma unroll 4
  for (int b = 0; b < HBLK; b++) tot += hist[b * 256 + d];
  sc[d] = tot;
  __syncthreads();
  for (int off = 1; off < 256; off <<= 1) {
    int tv = (d >= off) ? sc[d - off] : 0;
    __syncthreads();
    sc[d] += tv;
    __syncthreads();
  }
  const int excl = sc[d] - tot;
  bucket_base[d] = excl;
  if (d == 255) {
    bucket_base[256] = sc[255];
    rowp[N] = sc[255];   // == ET
  }
  int run = excl;
#pragma unroll 4
  for (int b = 0; b < HBLK; b++) {
    int v = hist[b * 256 + d];
    base[b * 256 + d] = run;
    run += v;
  }
}

__global__ void coarse_scatter_kernel(const int* __restrict__ ei, const int* __restrict__ base,
                                      uint32_t* __restrict__ keys) {
  __shared__ int cnt[256];
  const int t = threadIdx.x;
  cnt[t] = base[blockIdx.x * 256 + t];
  __syncthreads();
  const int cbase = blockIdx.x * EPB2;
  const int cend = (cbase + EPB2 < ET) ? (cbase + EPB2) : ET;
  for (int e0 = cbase + t * 4; e0 < cend; e0 += 1024) {
    if (e0 + 3 < E && e0 + 3 < cend) {
      int4 dv = *reinterpret_cast<const int4*>(ei + E + e0);
      int4 sv = *reinterpret_cast<const int4*>(ei + e0);
      int p0 = atomicAdd(&cnt[dv.x >> 8], 1);
      keys[p0] = ((uint32_t)dv.x << 16) | (uint32_t)sv.x;
      int p1 = atomicAdd(&cnt[dv.y >> 8], 1);
      keys[p1] = ((uint32_t)dv.y << 16) | (uint32_t)sv.y;
      int p2 = atomicAdd(&cnt[dv.z >> 8], 1);
      keys[p2] = ((uint32_t)dv.z << 16) | (uint32_t)sv.z;
      int p3 = atomicAdd(&cnt[dv.w >> 8], 1);
      keys[p3] = ((uint32_t)dv.w << 16) | (uint32_t)sv.w;
    } else {
#pragma unroll
      for (int q = 0; q < 4; q++) {
        int e = e0 + q;
        if (e < cend) {
          int dd, ssrc;
          if (e < E) { dd = ei[E + e]; ssrc = ei[e]; }
          else       { dd = e - E; ssrc = e - E; }
          int p = atomicAdd(&cnt[dd >> 8], 1);
          keys[p] = ((uint32_t)dd << 16) | (uint32_t)ssrc;
        }
      }
    }
  }
}

// bucket sort + fused degree histogram (for the LPT permutation)
__global__ void bucket_sort_kernel(const uint32_t* __restrict__ keys,
                                   const int* __restrict__ bucket_base,
                                   int* __restrict__ rowp, uint16_t* __restrict__ col,
                                   int* __restrict__ dh) {
  __shared__ int hist[256];
  __shared__ int sc[256];
  __shared__ int ofs[256];
  __shared__ int dhl[256];
  const int b = blockIdx.x;
  const int t = threadIdx.x;
  hist[t] = 0;
  dhl[t] = 0;
  __syncthreads();
  const int k0 = bucket_base[b], k1 = bucket_base[b + 1];
  for (int i = k0 + t; i < k1; i += 256)
    atomicAdd(&hist[(keys[i] >> 16) & 255], 1);
  __syncthreads();
  const int v = hist[t];
  sc[t] = v;
  __syncthreads();
  for (int off = 1; off < 256; off <<= 1) {
    int tv = (t >= off) ? sc[t - off] : 0;
    __syncthreads();
    sc[t] += tv;
    __syncthreads();
  }
  ofs[t] = k0 + sc[t] - v;
  const int node = b * 256 + t;
  if (node < N) {
    rowp[node] = ofs[t];
    int dv = (v > 255) ? 255 : v;
    atomicAdd(&dhl[dv], 1);        // degree histogram (real nodes only)
  }
  hist[t] = 0;
  __syncthreads();
  for (int i = k0 + t; i < k1; i += 256) {
    uint32_t key = keys[i];
    int loc = (key >> 16) & 255;
    int p = ofs[loc] + atomicAdd(&hist[loc], 1);
    col[p] = (uint16_t)(key & 0xFFFFu);
  }
  __syncthreads();
  dh[b * 256 + t] = dhl[t];
}

// ======== degree-sorted node permutation, DESCENDING (LPT scheduling) ========

__global__ void deg_scan_kernel(const int* __restrict__ dh, int* __restrict__ dbase) {
  __shared__ int sc[256];
  const int d = threadIdx.x;
  int tot = 0;
#pragma unroll 4
  for (int b = 0; b < NBUCK; b++) tot += dh[b * 256 + d];
  sc[d] = tot;
  __syncthreads();
  for (int off = 1; off < 256; off <<= 1) {
    int tv = (d >= off) ? sc[d - off] : 0;
    __syncthreads();
    sc[d] += tv;
    __syncthreads();
  }
  int run = sc[d] - tot;
#pragma unroll 4
  for (int b = 0; b < NBUCK; b++) {
    int v = dh[b * 256 + d];
    dbase[b * 256 + d] = run;
    run += v;
  }
}

__global__ void deg_scatter_kernel(const int* __restrict__ rowp, const int* __restrict__ dbase,
                                   int* __restrict__ perm) {
  __shared__ int cnt[256];
  const int t = threadIdx.x;
  cnt[t] = dbase[blockIdx.x * 256 + t];
  __syncthreads();
  int i = blockIdx.x * 256 + t;
  if (i < N) {
    int deg = rowp[i + 1] - rowp[i];
    if (deg > 255) deg = 255;
    int p = atomicAdd(&cnt[deg], 1);
    perm[N - 1 - p] = i;            // descending degree -> LPT dispatch
  }
}

// ------- union prep: x -> bf16 pairs, and W1..W4 -> bf16 W^T -------

constexpr int TOB_N2 = N * (F / 2);                       // 6.4M u32
constexpr int T1 = 96 * 256, T2 = 96 * 96, T3 = 96 * 96, T4 = 48 * 96;
constexpr int CVT_T = T1 + T2 + T3 + T4;

__global__ void prep_kernel(const float* __restrict__ x, uint32_t* __restrict__ xB,
                            const float* __restrict__ W1, const float* __restrict__ W2,
                            const float* __restrict__ W3, const float* __restrict__ W4,
                            uint16_t* __restrict__ WT1, uint16_t* __restrict__ WT2,
                            uint16_t* __restrict__ WT3, uint16_t* __restrict__ WT4) {
  int t = blockIdx.x * 256 + threadIdx.x;
  if (t < TOB_N2) {
    float2 v = reinterpret_cast<const float2*>(x)[t];
    xB[t] = (f2bf(v.y) << 16) | f2bf(v.x);
    return;
  }
  t -= TOB_N2;
  if (t < T1) {
    int n = t / 256, k = t % 256;
    WT1[t] = (uint16_t)f2bf(W1[(size_t)k * 96 + n]);
  } else if (t < T1 + T2) {
    int u = t - T1; int n = u / 96, k = u % 96;
    WT2[u] = (uint16_t)f2bf(W2[(size_t)k * 96 + n]);
  } else if (t < T1 + T2 + T3) {
    int u = t - T1 - T2; int n = u / 96, k = u % 96;
    WT3[u] = (uint16_t)f2bf(W3[(size_t)k * 96 + n]);
  } else if (t < CVT_T) {
    int u = t - T1 - T2 - T3; int n = u / 96, k = u % 96;
    WT4[u] = (n < K) ? (uint16_t)f2bf(W4[(size_t)k * K + n]) : (uint16_t)0;
  }
}

// ---- fused MFMA GEMM + fp8-record pack (hidden layers, NCOLS=96) ----

template <int KD>
__launch_bounds__(256)
__global__ void gemm_pack_kernel(const uint32_t* __restrict__ A,
                                 const uint16_t* __restrict__ WT,
                                 const float* __restrict__ as_,
                                 const float* __restrict__ ad_,
                                 uint32_t* __restrict__ recs,
                                 float* __restrict__ aldP) {
  constexpr int KU = KD / 2;
  __shared__ float lds[64][97];
  const int wave = threadIdx.x >> 6;
  const int lane = threadIdx.x & 63;
  const int r = lane & 15, g = lane >> 4;
  const int m0 = (blockIdx.x * 4 + wave) * 16;
  int rowA = m0 + r;
  if (rowA > N - 1) rowA = N - 1;
  const uint32_t* arow = A + (size_t)rowA * KU + g * 4;
  const uint32_t* wt32 = reinterpret_cast<const uint32_t*>(WT);

  f32x4 acc[6];
#pragma unroll
  for (int nt = 0; nt < 6; nt++) acc[nt] = (f32x4){0.f, 0.f, 0.f, 0.f};

#pragma unroll
  for (int ks = 0; ks < KD / 32; ks++) {
    short8 av = *reinterpret_cast<const short8*>(arow + ks * 16);
#pragma unroll
    for (int nt = 0; nt < 6; nt++) {
      short8 bv = *reinterpret_cast<const short8*>(
          wt32 + (size_t)(nt * 16 + r) * KU + ks * 16 + g * 4);
      acc[nt] = __builtin_amdgcn_mfma_f32_16x16x32_bf16(av, bv, acc[nt], 0, 0, 0);
    }
  }

  const int lr0 = wave * 16 + g * 4;
#pragma unroll
  for (int nt = 0; nt < 6; nt++) {
#pragma unroll
    for (int t = 0; t < 4; t++) lds[lr0 + t][nt * 16 + r] = acc[nt][t];
  }
  __syncthreads();

  const int row = threadIdx.x >> 2;   // 0..63
  const int q = threadIdx.x & 3;      // 0..3
  const int grow = blockIdx.x * 64 + row;
  if (grow < N) {
    const float* lr = lds[row];
    uint32_t* rp = recs + (size_t)grow * 32;
#pragma unroll
    for (int w = 0; w < 6; w++) {
      const int c0 = q * 24 + w * 4;
      uint32_t wv = 0;
      wv = (uint32_t)__builtin_amdgcn_cvt_pk_fp8_f32(lr[c0], lr[c0 + 1], (int)wv, false);
      wv = (uint32_t)__builtin_amdgcn_cvt_pk_fp8_f32(lr[c0 + 2], lr[c0 + 3], (int)wv, true);
      rp[q * 6 + w] = wv;
    }
#pragma unroll
    for (int i = 0; i < 3; i++) {
      const int d = q * 3 + i;        // 12 dots: (head, s/d)
      const int hh = d >> 1;
      const float* av = (d & 1) ? ad_ : as_;
      float s = 0.f;
#pragma unroll
      for (int c = 0; c < 16; c++) s += lr[hh * 16 + c] * av[hh * 16 + c];
      if (d & 1) aldP[(size_t)grow * 8 + hh] = s;
      else       rp[24 + hh] = __float_as_uint(s);
    }
  }
}

// ---- fused MFMA GEMM + pack for layer 4 (KD=96 -> 40 ch, 64B records) ----

__launch_bounds__(256)
__global__ void gemm_pack4_kernel(const uint32_t* __restrict__ A,
                                  const uint16_t* __restrict__ WT,
                                  const float* __restrict__ as_,
                                  const float* __restrict__ ad_,
                                  uint32_t* __restrict__ recs4,
                                  float* __restrict__ ald4) {
  constexpr int KU = 48;              // 96 bf16 = 48 u32 per row
  __shared__ float lds[64][49];
  const int wave = threadIdx.x >> 6;
  const int lane = threadIdx.x & 63;
  const int r = lane & 15, g = lane >> 4;
  const int m0 = (blockIdx.x * 4 + wave) * 16;
  int rowA = m0 + r;
  if (rowA > N - 1) rowA = N - 1;
  const uint32_t* arow = A + (size_t)rowA * KU + g * 4;
  const uint32_t* wt32 = reinterpret_cast<const uint32_t*>(WT);

  f32x4 acc[3];
#pragma unroll
  for (int nt = 0; nt < 3; nt++) acc[nt] = (f32x4){0.f, 0.f, 0.f, 0.f};

#pragma unroll
  for (int ks = 0; ks < 3; ks++) {
    short8 av = *reinterpret_cast<const short8*>(arow + ks * 16);
#pragma unroll
    for (int nt = 0; nt < 3; nt++) {
      short8 bv = *reinterpret_cast<const short8*>(
          wt32 + (size_t)(nt * 16 + r) * KU + ks * 16 + g * 4);
      acc[nt] = __builtin_amdgcn_mfma_f32_16x16x32_bf16(av, bv, acc[nt], 0, 0, 0);
    }
  }

  const int lr0 = wave * 16 + g * 4;
#pragma unroll
  for (int nt = 0; nt < 3; nt++) {
#pragma unroll
    for (int t = 0; t < 4; t++) lds[lr0 + t][nt * 16 + r] = acc[nt][t];
  }
  __syncthreads();

  if (threadIdx.x < 64) {
    const int row = threadIdx.x;
    const int grow = blockIdx.x * 64 + row;
    if (grow < N) {
      const float* lr = lds[row];
      float ss = 0.f, dd = 0.f;
#pragma unroll
      for (int c = 0; c < 40; c++) {
        ss += lr[c] * as_[c];
        dd += lr[c] * ad_[c];
      }
      uint32_t* rp = recs4 + (size_t)grow * 16;
#pragma unroll
      for (int q = 0; q < 10; q++) {
        uint32_t w = 0;
        w = (uint32_t)__builtin_amdgcn_cvt_pk_fp8_f32(lr[4 * q], lr[4 * q + 1], (int)w, false);
        w = (uint32_t)__builtin_amdgcn_cvt_pk_fp8_f32(lr[4 * q + 2], lr[4 * q + 3], (int)w, true);
        rp[q] = w;
      }
      rp[10] = __float_as_uint(ss);
      ald4[grow] = dd;
    }
  }
}

// ------- degree-sorted (descending) multi-node-per-wave flash aggregate -------

template <int LPN, int NPW, int REC32, int ALSW, int HDIV, int PAD, bool LSM>
__launch_bounds__(256)
__global__ void flash_agg5_kernel(const uint32_t* __restrict__ recs,
                                  const int* __restrict__ rowp,
                                  const uint16_t* __restrict__ col,
                                  const int* __restrict__ perm,
                                  const float* __restrict__ aldP,
                                  const float* __restrict__ bias,
                                  uint4* __restrict__ outB4,
                                  float* __restrict__ outF32) {
  const int lane = threadIdx.x & 63;
  const int wave = threadIdx.x >> 6;
  int g = lane / LPN;
  const int li = lane - g * LPN;
  if (g > NPW - 1) g = NPW - 1;
  int idx = (blockIdx.x * 4 + wave) * NPW + g;
  if (idx > N - 1) idx = N - 1;
  const int n = perm[idx];
  const int hh = li / HDIV;
  const float aldv = aldP[(size_t)n * PAD + hh];
  const int b0 = rowp[n];
  const int deg = rowp[n + 1] - b0;
  const int d1 = deg >> 1;        // half A: [0,d1)
  const int d2 = deg - d1;        // half B: [d1,deg)

  int km = d2;
#pragma unroll
  for (int off = 32; off > 0; off >>= 1) {
    int o = __shfl_xor(km, off);
    km = (o > km) ? o : km;
  }

  float a0 = 0.f, a1 = 0.f, a2 = 0.f, a3 = 0.f;
  float a4 = 0.f, a5 = 0.f, a6 = 0.f, a7 = 0.f;
  float b0f = 0.f, b1f = 0.f, b2f = 0.f, b3f = 0.f;
  float b4f = 0.f, b5f = 0.f, b6f = 0.f, b7f = 0.f;
  float ssA = 0.f, ssB = 0.f;

#pragma unroll 4
  for (int k = 0; k < km; k++) {
    const bool vA = (k < d1);
    const bool vB = (k < d2);
    const int jA = b0 + (vA ? k : 0);
    const int jB = b0 + d1 + (vB ? k : 0);
    const int srcA = (int)col[jA];
    const int srcB = (int)col[jB];
    const uint32_t* recA = recs + (size_t)srcA * REC32;
    const uint32_t* recB = recs + (size_t)srcB * REC32;
    uint2 uA = *reinterpret_cast<const uint2*>(recA + 2 * li);
    uint2 uB = *reinterpret_cast<const uint2*>(recB + 2 * li);
    float lA = __uint_as_float(recA[ALSW + hh]);
    float lB = __uint_as_float(recB[ALSW + hh]);
    float eA = lA + aldv; eA = fmaxf(eA, 0.2f * eA);
    float eB = lB + aldv; eB = fmaxf(eB, 0.2f * eB);
    float pA = __expf(eA); pA = vA ? pA : 0.f;
    float pB = __expf(eB); pB = vB ? pB : 0.f;
    f32x2 cA0 = __builtin_amdgcn_cvt_pk_f32_fp8((int)uA.x, false);
    f32x2 cA1 = __builtin_amdgcn_cvt_pk_f32_fp8((int)uA.x, true);
    f32x2 cA2 = __builtin_amdgcn_cvt_pk_f32_fp8((int)uA.y, false);
    f32x2 cA3 = __builtin_amdgcn_cvt_pk_f32_fp8((int)uA.y, true);
    f32x2 cB0 = __builtin_amdgcn_cvt_pk_f32_fp8((int)uB.x, false);
    f32x2 cB1 = __builtin_amdgcn_cvt_pk_f32_fp8((int)uB.x, true);
    f32x2 cB2 = __builtin_amdgcn_cvt_pk_f32_fp8((int)uB.y, false);
    f32x2 cB3 = __builtin_amdgcn_cvt_pk_f32_fp8((int)uB.y, true);
    a0 += pA * cA0.x; a1 += pA * cA0.y;
    a2 += pA * cA1.x; a3 += pA * cA1.y;
    a4 += pA * cA2.x; a5 += pA * cA2.y;
    a6 += pA * cA3.x; a7 += pA * cA3.y;
    ssA += pA;
    b0f += pB * cB0.x; b1f += pB * cB0.y;
    b2f += pB * cB1.x; b3f += pB * cB1.y;
    b4f += pB * cB2.x; b5f += pB * cB2.y;
    b6f += pB * cB3.x; b7f += pB * cB3.y;
    ssB += pB;
  }

  a0 += b0f; a1 += b1f; a2 += b2f; a3 += b3f;
  a4 += b4f; a5 += b5f; a6 += b6f; a7 += b7f;
  float inv = 1.f / (ssA + ssB + 1e-16f);

  if (!LSM) {
    float o0 = fmaxf(a0 * inv + bias[8 * li + 0], 0.f);
    float o1 = fmaxf(a1 * inv + bias[8 * li + 1], 0.f);
    float o2 = fmaxf(a2 * inv + bias[8 * li + 2], 0.f);
    float o3 = fmaxf(a3 * inv + bias[8 * li + 3], 0.f);
    float o4 = fmaxf(a4 * inv + bias[8 * li + 4], 0.f);
    float o5 = fmaxf(a5 * inv + bias[8 * li + 5], 0.f);
    float o6 = fmaxf(a6 * inv + bias[8 * li + 6], 0.f);
    float o7 = fmaxf(a7 * inv + bias[8 * li + 7], 0.f);
    uint4 w;
    w.x = (f2bf(o1) << 16) | f2bf(o0);
    w.y = (f2bf(o3) << 16) | f2bf(o2);
    w.z = (f2bf(o5) << 16) | f2bf(o4);
    w.w = (f2bf(o7) << 16) | f2bf(o6);
    outB4[(size_t)n * LPN + li] = w;
  } else {
    bool vl = (li < 5);
    float v0 = vl ? a0 * inv + bias[8 * li + 0] : -1e30f;
    float v1 = vl ? a1 * inv + bias[8 * li + 1] : -1e30f;
    float v2 = vl ? a2 * inv + bias[8 * li + 2] : -1e30f;
    float v3 = vl ? a3 * inv + bias[8 * li + 3] : -1e30f;
    float v4 = vl ? a4 * inv + bias[8 * li + 4] : -1e30f;
    float v5 = vl ? a5 * inv + bias[8 * li + 5] : -1e30f;
    float v6 = vl ? a6 * inv + bias[8 * li + 6] : -1e30f;
    float v7 = vl ? a7 * inv + bias[8 * li + 7] : -1e30f;
    float mx = fmaxf(fmaxf(fmaxf(v0, v1), fmaxf(v2, v3)),
                     fmaxf(fmaxf(v4, v5), fmaxf(v6, v7)));
#pragma unroll
    for (int off = 1; off < 8; off <<= 1) mx = fmaxf(mx, __shfl_xor(mx, off));
    float es = 0.f;
    if (vl)
      es = __expf(v0 - mx) + __expf(v1 - mx) + __expf(v2 - mx) + __expf(v3 - mx) +
           __expf(v4 - mx) + __expf(v5 - mx) + __expf(v6 - mx) + __expf(v7 - mx);
#pragma unroll
    for (int off = 1; off < 8; off <<= 1) es += __shfl_xor(es, off);
    float lse = mx + __logf(es);
    if (vl) {
      float* op = outF32 + (size_t)n * K + li * 8;
      float4 w0 = make_float4(v0 - lse, v1 - lse, v2 - lse, v3 - lse);
      float4 w1 = make_float4(v4 - lse, v5 - lse, v6 - lse, v7 - lse);
      *reinterpret_cast<float4*>(op) = w0;
      *reinterpret_cast<float4*>(op + 4) = w1;
    }
  }
}

inline int cdiv(int a, int b) { return (a + b - 1) / b; }

}  // namespace

extern "C" void kernel_launch(void* const* d_in, const int* in_sizes, int n_in,
                              void* d_out, int out_size, void* d_ws, size_t ws_size,
                              hipStream_t stream) {
  (void)in_sizes; (void)n_in; (void)out_size; (void)ws_size;
  const float* x   = (const float*)d_in[0];
  const int*   ei  = (const int*)d_in[1];
  const float* W1  = (const float*)d_in[2];
  const float* a1s = (const float*)d_in[3];
  const float* a1d = (const float*)d_in[4];
  const float* b1  = (const float*)d_in[5];
  const float* W2  = (const float*)d_in[6];
  const float* a2s = (const float*)d_in[7];
  const float* a2d = (const float*)d_in[8];
  const float* b2  = (const float*)d_in[9];
  const float* W3  = (const float*)d_in[10];
  const float* a3s = (const float*)d_in[11];
  const float* a3d = (const float*)d_in[12];
  const float* b3  = (const float*)d_in[13];
  const float* W4  = (const float*)d_in[14];
  const float* a4s = (const float*)d_in[15];
  const float* a4d = (const float*)d_in[16];
  const float* b4  = (const float*)d_in[17];
  float* out = (float*)d_out;

  char* ws = (char*)d_ws;
  size_t off = 0;
  auto alloc = [&](size_t bytes) {
    void* p = ws + off;
    off = (off + bytes + 255) & ~(size_t)255;
    return p;
  };
  int*      hist  = (int*)alloc((size_t)HBLK * 256 * 4);
  int*      basep = (int*)alloc((size_t)HBLK * 256 * 4);
  int*      bbase = (int*)alloc((size_t)257 * 4);
  int*      rowp  = (int*)alloc((size_t)(N + 1) * 4);
  uint32_t* keys  = (uint32_t*)alloc((size_t)ET * 4);
  uint16_t* col   = (uint16_t*)alloc((size_t)ET * 2);
  int*      perm  = (int*)alloc((size_t)N * 4);
  uint32_t* xB    = (uint32_t*)alloc((size_t)N * (F / 2) * 4);
  uint16_t* WT1   = (uint16_t*)alloc((size_t)96 * 256 * 2);
  uint16_t* WT2   = (uint16_t*)alloc((size_t)96 * 96 * 2);
  uint16_t* WT3   = (uint16_t*)alloc((size_t)96 * 96 * 2);
  uint16_t* WT4   = (uint16_t*)alloc((size_t)48 * 96 * 2);
  uint32_t* actB  = (uint32_t*)alloc((size_t)N * (HC / 2) * 4);
  uint32_t* recs  = (uint32_t*)alloc((size_t)N * 32 * 4);   // 128B records (fp8 h + als)
  uint32_t* recs4 = (uint32_t*)alloc((size_t)N * 16 * 4);   // 64B records (L4)
  float*    aldP  = (float*)alloc((size_t)N * 8 * 4);

  // ---- build CSR: LDS counting sort, zero global atomics ----
  coarse_hist_kernel<<<HBLK, 256, 0, stream>>>(ei, hist);
  coarse_scan_kernel<<<1, 256, 0, stream>>>(hist, basep, bbase, rowp);
  coarse_scatter_kernel<<<HBLK, 256, 0, stream>>>(ei, basep, keys);
  bucket_sort_kernel<<<NBUCK, 256, 0, stream>>>(keys, bbase, rowp, col, hist);

  // ---- degree-sorted node permutation, descending (dh lives in hist) ----
  deg_scan_kernel<<<1, 256, 0, stream>>>(hist, basep);
  deg_scatter_kernel<<<NBUCK, 256, 0, stream>>>(rowp, basep, perm);

  // ---- dtype prep (x -> bf16, W -> W^T bf16) ----
  prep_kernel<<<cdiv(TOB_N2 + CVT_T, 256), 256, 0, stream>>>(
      x, xB, W1, W2, W3, W4, WT1, WT2, WT3, WT4);

  const int gG   = cdiv(N, 64);     // GEMM: 4 waves x 16 rows per block
  const int gA96 = cdiv(N, 20);     // agg L1-3: 4 waves x 5 nodes
  const int gA40 = cdiv(N, 32);     // agg L4:   4 waves x 8 nodes

  // ---- layer 1 ----
  gemm_pack_kernel<F><<<gG, 256, 0, stream>>>(xB, WT1, a1s, a1d, recs, aldP);
  flash_agg5_kernel<12, 5, 32, 24, 2, 8, false><<<gA96, 256, 0, stream>>>(
      recs, rowp, col, perm, aldP, b1, (uint4*)actB, nullptr);

  // ---- layer 2 ----
  gemm_pack_kernel<HC><<<gG, 256, 0, stream>>>(actB, WT2, a2s, a2d, recs, aldP);
  flash_agg5_kernel<12, 5, 32, 24, 2, 8, false><<<gA96, 256, 0, stream>>>(
      recs, rowp, col, perm, aldP, b2, (uint4*)actB, nullptr);

  // ---- layer 3 ----
  gemm_pack_kernel<HC><<<gG, 256, 0, stream>>>(actB, WT3, a3s, a3d, recs, aldP);
  flash_agg5_kernel<12, 5, 32, 24, 2, 8, false><<<gA96, 256, 0, stream>>>(
      recs, rowp, col, perm, aldP, b3, (uint4*)actB, nullptr);

  // ---- layer 4: fused GEMM+pack, aggregate + log_softmax ----
  gemm_pack4_kernel<<<gG, 256, 0, stream>>>(actB, WT4, a4s, a4d, recs4, aldP);
  flash_agg5_kernel<8, 8, 16, 10, 16, 1, true><<<gA40, 256, 0, stream>>>(
      recs4, rowp, col, perm, aldP, b4, nullptr, out);
}